// Round 2
// baseline (4901.130 us; speedup 1.0000x reference)
//
#include <hip/hip_runtime.h>
#include <math.h>

// ---- problem constants ----
#define Bb   16
#define Ll   256      // U = E
#define Cd   256
#define Hh   8
#define Dd   32
#define Md   1024
#define Pp   32
#define OUTd 256
#define OHd  32
#define FINd 5
#define Fd   1057     // 4*C + OH + 1
#define NEG_HUGE (-3.402823466e38f)

// ---- workspace layout (float offsets) ----
#define WS_ENC  0u            // 2B*L*C = 2,097,152
#define WS_PAIR 2097152u      // B*L*L  = 1,048,576
#define WS_BIG  3145728u      // 8,388,608 (q,k,v,o / mlp hidden / gate)
#define WS_SP   11534336u     // 2B*L*P = 262,144
#define WS_GU   11796480u     // B*L
#define WS_GE   11800576u     // B*L
#define WS_UG   11804672u     // 2B*L
#define WS_FV   11812864u     // B*Fd

// =====================================================================
// GEMM core: C[64x64 tile] = alpha*(A@W + bias) (+relu) (+resid)
// A: [rows][lda] (K along lda), W: [K][ldw], C/resid: [rows][ldc]
// =====================================================================
template<bool RELU, bool RESID>
__device__ __forceinline__ void gemm_core(
    const float* __restrict__ A, int lda,
    const float* __restrict__ W, int ldw,
    const float* __restrict__ bias,
    float* __restrict__ Cp, int ldc,
    const float* __restrict__ resid,
    int K, float alpha)
{
  __shared__ float As[32][68];   // [k][row]  (transposed, pad 68 for b128-aligned reads)
  __shared__ float Bs[32][68];   // [k][col]
  const int tid  = threadIdx.x;
  const int row0 = blockIdx.y * 64;
  const int col0 = blockIdx.x * 64;
  const int tr = tid >> 4, tc = tid & 15;
  float acc[4][4] = {};
  for (int k0 = 0; k0 < K; k0 += 32) {
    #pragma unroll
    for (int t = 0; t < 8; ++t) {
      int idx = t * 256 + tid;
      int ra = idx >> 5, ka = idx & 31;
      As[ka][ra] = A[(size_t)(row0 + ra) * lda + (k0 + ka)];
      int kb = idx >> 6, cb = idx & 63;
      Bs[kb][cb] = W[(size_t)(k0 + kb) * ldw + (col0 + cb)];
    }
    __syncthreads();
    #pragma unroll
    for (int kk = 0; kk < 32; ++kk) {
      float4 av = *(const float4*)&As[kk][tr * 4];
      float4 bv = *(const float4*)&Bs[kk][tc * 4];
      float aa[4] = {av.x, av.y, av.z, av.w};
      float bb[4] = {bv.x, bv.y, bv.z, bv.w};
      #pragma unroll
      for (int i = 0; i < 4; ++i)
        #pragma unroll
        for (int j = 0; j < 4; ++j)
          acc[i][j] = fmaf(aa[i], bb[j], acc[i][j]);
    }
    __syncthreads();
  }
  float4 bv4 = *(const float4*)&bias[col0 + tc * 4];
  float bb[4] = {bv4.x, bv4.y, bv4.z, bv4.w};
  #pragma unroll
  for (int i = 0; i < 4; ++i) {
    int r = row0 + tr * 4 + i;
    float v[4];
    #pragma unroll
    for (int j = 0; j < 4; ++j) {
      v[j] = alpha * (acc[i][j] + bb[j]);
      if (RELU) v[j] = fmaxf(v[j], 0.f);
    }
    if (RESID) {
      float4 rv = *(const float4*)&resid[(size_t)r * ldc + col0 + tc * 4];
      v[0] += rv.x; v[1] += rv.y; v[2] += rv.z; v[3] += rv.w;
    }
    float4 ov = {v[0], v[1], v[2], v[3]};
    *(float4*)&Cp[(size_t)r * ldc + col0 + tc * 4] = ov;
  }
}

// qkv projection: grid (4,4,96): z -> n(0..31), proj(0..2).  q gets alpha=scale.
__global__ __launch_bounds__(256) void k_gemm_qkv(
    const float* __restrict__ enc,
    const float* __restrict__ wq, const float* __restrict__ bq,
    const float* __restrict__ wk, const float* __restrict__ bk,
    const float* __restrict__ wv, const float* __restrict__ bv,
    float* __restrict__ q, float* __restrict__ k, float* __restrict__ v, float scale)
{
  int z = blockIdx.z;
  int n = z / 3, pr = z % 3;
  const float* W; const float* bias; float* out; float alpha = 1.f;
  if (pr == 0)      { W = wq; bias = bq; out = q; alpha = scale; }
  else if (pr == 1) { W = wk; bias = bk; out = k; }
  else              { W = wv; bias = bv; out = v; }
  size_t off = (size_t)n * Ll * Cd;
  gemm_core<false,false>(enc + off, Cd, W, Cd, bias, out + off, Cd, nullptr, Cd, alpha);
}

// out-projection + residual: grid (4,4,32)
__global__ __launch_bounds__(256) void k_gemm_out(
    const float* __restrict__ ob, const float* __restrict__ wo,
    const float* __restrict__ bo, float* __restrict__ enc)
{
  size_t off = (size_t)blockIdx.z * Ll * Cd;
  gemm_core<false,true>(ob + off, Cd, wo, Cd, bo, enc + off, Cd, enc + off, Cd, 1.f);
}

// mlp in (relu): grid (16,4,32)
__global__ __launch_bounds__(256) void k_gemm_mlpin(
    const float* __restrict__ enc, const float* __restrict__ win,
    const float* __restrict__ bin, float* __restrict__ h)
{
  size_t offa = (size_t)blockIdx.z * Ll * Cd;
  size_t offc = (size_t)blockIdx.z * Ll * Md;
  gemm_core<true,false>(enc + offa, Cd, win, Md, bin, h + offc, Md, nullptr, Cd, 1.f);
}

// mlp out + residual: grid (4,4,32)
__global__ __launch_bounds__(256) void k_gemm_mlpout(
    const float* __restrict__ h, const float* __restrict__ wout,
    const float* __restrict__ bout, float* __restrict__ enc)
{
  size_t offa = (size_t)blockIdx.z * Ll * Md;
  size_t offc = (size_t)blockIdx.z * Ll * Cd;
  gemm_core<false,true>(h + offa, Md, wout, Cd, bout, enc + offc, Cd, enc + offc, Md, 1.f);
}

// =====================================================================
// LayerNorm in-place over C=256, wave per row. grid 2048 x 256thr
// =====================================================================
__global__ __launch_bounds__(256) void k_ln(float* __restrict__ enc,
    const float* __restrict__ s, const float* __restrict__ b2)
{
  int tid = threadIdx.x;
  int r = blockIdx.x * 4 + (tid >> 6);
  int lane = tid & 63;
  float* row = enc + (size_t)r * Cd;
  float4 v = ((float4*)row)[lane];
  float p = v.x + v.y + v.z + v.w;
  #pragma unroll
  for (int m = 1; m < 64; m <<= 1) p += __shfl_xor(p, m);
  float mu = p * (1.f / 256.f);
  float dx = v.x - mu, dy = v.y - mu, dz = v.z - mu, dw = v.w - mu;
  float q = dx*dx + dy*dy + dz*dz + dw*dw;
  #pragma unroll
  for (int m = 1; m < 64; m <<= 1) q += __shfl_xor(q, m);
  float rstd = rsqrtf(q * (1.f / 256.f) + 1e-6f);
  float4 sv = ((const float4*)s)[lane];
  float4 bv = ((const float4*)b2)[lane];
  v.x = sv.x * dx * rstd + bv.x;
  v.y = sv.y * dy * rstd + bv.y;
  v.z = sv.z * dz * rstd + bv.z;
  v.w = sv.w * dw * rstd + bv.w;
  ((float4*)row)[lane] = v;
}

// =====================================================================
// Attention. grid (2B, H), 256 thr; thread = one query row.
// CROSS=1: kv from opposite side, +bpp-pair bias, post-mask rows.
// CROSS=0: kv same side, no bias, no post-mask (uniform for invalid rows,
//          exactly matching the reference's NINF semantics).
// =====================================================================
template<int CROSS>
__global__ __launch_bounds__(256) void k_attn(
    const float* __restrict__ qb, const float* __restrict__ kb,
    const float* __restrict__ vb, float* __restrict__ ob,
    const float* __restrict__ pair,
    const float* __restrict__ bw_p, const float* __restrict__ bb_p,
    const int* __restrict__ ulp, const int* __restrict__ elp)
{
  __shared__ float ks_[32][32];
  __shared__ float vs_[32][32];
  __shared__ float ps[CROSS ? Ll * 33 : 1];
  const int tid = threadIdx.x;
  const int n = blockIdx.x, h = blockIdx.y;
  const int b = n >> 1, s = n & 1;
  const int u_len = ulp[0], e_len = elp[0];
  const int nkv = CROSS ? (b * 2 + 1 - s) : n;
  const int qlen  = s ? e_len : u_len;
  const int kvlen = CROSS ? (s ? u_len : e_len) : qlen;
  const float* qp = qb + (size_t)n   * Ll * Cd + h * Dd;
  const float* kp = kb + (size_t)nkv * Ll * Cd + h * Dd;
  const float* vp = vb + (size_t)nkv * Ll * Cd + h * Dd;
  float bw = 0.f, bbias = 0.f;
  if (CROSS) { bw = bw_p[0]; bbias = bb_p[0]; }

  float qv[32];
  {
    const float4* q4 = (const float4*)(qp + (size_t)tid * Cd);
    #pragma unroll
    for (int t = 0; t < 8; ++t) {
      float4 x = q4[t];
      qv[4*t] = x.x; qv[4*t+1] = x.y; qv[4*t+2] = x.z; qv[4*t+3] = x.w;
    }
  }
  const bool qvalid = tid < qlen;
  float m = NEG_HUGE, l = 0.f;
  float oa[32];
  #pragma unroll
  for (int d = 0; d < 32; ++d) oa[d] = 0.f;

  for (int e0 = 0; e0 < Ll; e0 += 32) {
    __syncthreads();
    // stage K,V chunk (32 keys x 32 dims)
    #pragma unroll
    for (int t = 0; t < 4; ++t) {
      int idx = t * 256 + tid;
      int r = idx >> 5, d = idx & 31;
      ks_[r][d] = kp[(size_t)(e0 + r) * Cd + d];
      vs_[r][d] = vp[(size_t)(e0 + r) * Cd + d];
    }
    if (CROSS) {
      if (s == 0) {
        for (int t = 0; t < 32; ++t) {
          int idx = t * 256 + tid;
          int r = idx >> 5, ec = idx & 31;
          ps[r * 33 + ec] = pair[((size_t)b * Ll + r) * Ll + (e0 + ec)];
        }
      } else {
        for (int t = 0; t < 32; ++t) {
          int idx = t * 256 + tid;
          int ec = idx >> 8, r = idx & 255;
          ps[r * 33 + ec] = pair[((size_t)b * Ll + e0 + ec) * Ll + r];
        }
      }
    }
    __syncthreads();
    #pragma unroll 2
    for (int ec = 0; ec < 32; ++ec) {
      int e = e0 + ec;
      float s0 = 0.f, s1 = 0.f, s2 = 0.f, s3 = 0.f;
      const float4* kr = (const float4*)&ks_[ec][0];
      #pragma unroll
      for (int t = 0; t < 8; ++t) {
        float4 kx = kr[t];
        s0 = fmaf(qv[4*t],   kx.x, s0);
        s1 = fmaf(qv[4*t+1], kx.y, s1);
        s2 = fmaf(qv[4*t+2], kx.z, s2);
        s3 = fmaf(qv[4*t+3], kx.w, s3);
      }
      float sd = (s0 + s1) + (s2 + s3);
      if (CROSS) sd = fmaf(bw, ps[tid * 33 + ec], sd + bbias);
      bool valid = qvalid && (e < kvlen);
      float sv = valid ? sd : NEG_HUGE;
      if (sv > m) {
        float corr = __expf(m - sv);
        l *= corr;
        #pragma unroll
        for (int d = 0; d < 32; ++d) oa[d] *= corr;
        m = sv;
      }
      float p = __expf(sv - m);
      l += p;
      const float4* vr = (const float4*)&vs_[ec][0];
      #pragma unroll
      for (int t = 0; t < 8; ++t) {
        float4 vx = vr[t];
        oa[4*t]   = fmaf(p, vx.x, oa[4*t]);
        oa[4*t+1] = fmaf(p, vx.y, oa[4*t+1]);
        oa[4*t+2] = fmaf(p, vx.z, oa[4*t+2]);
        oa[4*t+3] = fmaf(p, vx.w, oa[4*t+3]);
      }
    }
  }
  float inv = 1.f / l;
  float om = (CROSS && !qvalid) ? 0.f : inv;   // cross: ue_m * softmax zeroes invalid rows
  float* op = ob + ((size_t)n * Ll + tid) * Cd + h * Dd;
  #pragma unroll
  for (int t = 0; t < 8; ++t) {
    float4 x = {oa[4*t] * inv * (om == 0.f ? 0.f : 1.f), oa[4*t+1] * om, oa[4*t+2] * om, oa[4*t+3] * om};
    x.x = oa[4*t] * om;
    ((float4*)op)[t] = x;
  }
}

// =====================================================================
// Embedding + PE + mask. grid 8192 x 256 (gid = n<<16 | row<<8 | c)
// =====================================================================
__global__ __launch_bounds__(256) void k_embed(
    const float* __restrict__ u_in, const float* __restrict__ e_in,
    const float* __restrict__ emb_w, const float* __restrict__ emb_b,
    const int* __restrict__ ulp, const int* __restrict__ elp,
    float* __restrict__ enc)
{
  int gid = blockIdx.x * 256 + threadIdx.x;
  int c = gid & 255;
  int row = (gid >> 8) & 255;
  int n = gid >> 16;
  int b = n >> 1, s = n & 1;
  const float* x = (s ? e_in : u_in) + ((size_t)b * Ll + row) * FINd;
  float acc = emb_b[c];
  #pragma unroll
  for (int f = 0; f < FINd; ++f) acc = fmaf(x[f], emb_w[f * Cd + c], acc);
  // div = exp(-ln(10000) * (2*(c>>1)) / 256) = 2^(-log2(10000)/256 * (2*(c>>1)))
  const float k2 = 0.051902826f;  // log2(10000)/256
  float dv = exp2f(-k2 * (float)(2 * (c >> 1)));
  float ang = (float)row * dv;
  float pe = ((c & 1) == 0) ? sinf(ang) : cosf(ang);
  int len = s ? elp[0] : ulp[0];
  enc[gid] = (row < len) ? (acc + pe) : 0.f;
}

// pair = logit(bpp) with EPS=1e-3. grid 4096 x 256
__global__ __launch_bounds__(256) void k_pairinit(
    const float* __restrict__ bpp, float* __restrict__ pair)
{
  int gid = blockIdx.x * 256 + threadIdx.x;
  float v = bpp[gid];
  pair[gid] = logf(v + 1e-3f) - logf(1.f - v + 1e-3f);
}

// proj to P=32 columns: sp[n][row][p] = enc[n][row] @ W + b.  grid 1024 x 256
__global__ __launch_bounds__(256) void k_proj32(
    const float* __restrict__ enc, const float* __restrict__ Wp,
    const float* __restrict__ bp, float* __restrict__ sp)
{
  int gid = blockIdx.x * 256 + threadIdx.x;
  int p = gid & 31;
  int grow = gid >> 5;
  const float4* x4 = (const float4*)(enc + (size_t)grow * Cd);
  float acc = bp[p];
  for (int c4 = 0; c4 < 64; ++c4) {
    float4 xv = x4[c4];
    int cb = c4 * 4;
    acc = fmaf(xv.x, Wp[(cb    ) * Pp + p], acc);
    acc = fmaf(xv.y, Wp[(cb + 1) * Pp + p], acc);
    acc = fmaf(xv.z, Wp[(cb + 2) * Pp + p], acc);
    acc = fmaf(xv.w, Wp[(cb + 3) * Pp + p], acc);
  }
  sp[(size_t)grow * Pp + p] = acc;
}

// MODE 0: pair += w * mask * (su@se^T)
// MODE 1: gate = mask ? sigmoid(w*pair + b + su@se^T) : 0
// grid (4,4,B), 256 thr, 64x64 tile, K=32
template<int MODE>
__global__ __launch_bounds__(256) void k_pairop(
    const float* __restrict__ sp, float* __restrict__ pair, float* __restrict__ gate,
    const float* __restrict__ w_p, const float* __restrict__ b_p,
    const int* __restrict__ ulp, const int* __restrict__ elp)
{
  __shared__ float su[32][36];
  __shared__ float se[32][36];
  const int tid = threadIdx.x;
  const int b = blockIdx.z;
  const int u0 = blockIdx.y * 64, e0 = blockIdx.x * 64;
  const float* spu = sp + ((size_t)(b * 2 + 0) * Ll + u0) * Pp;
  const float* spe = sp + ((size_t)(b * 2 + 1) * Ll + e0) * Pp;
  #pragma unroll
  for (int t = 0; t < 8; ++t) {
    int idx = t * 256 + tid;
    int r = idx >> 5, p = idx & 31;
    su[p][r] = spu[r * Pp + p];
    se[p][r] = spe[r * Pp + p];
  }
  __syncthreads();
  const int tr = tid >> 4, tc = tid & 15;
  float acc[4][4] = {};
  #pragma unroll
  for (int p = 0; p < 32; ++p) {
    float4 av = *(const float4*)&su[p][tr * 4];
    float4 bv = *(const float4*)&se[p][tc * 4];
    float aa[4] = {av.x, av.y, av.z, av.w};
    float bb[4] = {bv.x, bv.y, bv.z, bv.w};
    #pragma unroll
    for (int i = 0; i < 4; ++i)
      #pragma unroll
      for (int j = 0; j < 4; ++j)
        acc[i][j] = fmaf(aa[i], bb[j], acc[i][j]);
  }
  const int u_len = ulp[0], e_len = elp[0];
  const float w = w_p[0];
  const float bb2 = MODE ? b_p[0] : 0.f;
  #pragma unroll
  for (int i = 0; i < 4; ++i) {
    int u = u0 + tr * 4 + i;
    bool uval = u < u_len;
    size_t off = ((size_t)b * Ll + u) * Ll + e0 + tc * 4;
    float4 pr = *(const float4*)&pair[off];
    float pv[4] = {pr.x, pr.y, pr.z, pr.w};
    float out[4];
    #pragma unroll
    for (int j = 0; j < 4; ++j) {
      bool valid = uval && ((e0 + tc * 4 + j) < e_len);
      if (MODE == 0) {
        out[j] = pv[j] + w * (valid ? acc[i][j] : 0.f);
      } else {
        float z = fmaf(w, pv[j], bb2) + acc[i][j];
        out[j] = valid ? (1.f / (1.f + expf(-z))) : 0.f;
      }
    }
    float4 ov = {out[0], out[1], out[2], out[3]};
    if (MODE == 0) *(float4*)&pair[off] = ov;
    else           *(float4*)&gate[off] = ov;
  }
}

// gate row/col sums. grid B x 256
__global__ __launch_bounds__(256) void k_sums(
    const float* __restrict__ gate, float* __restrict__ gu, float* __restrict__ ge)
{
  int b = blockIdx.x, tid = threadIdx.x;
  const float* g = gate + (size_t)b * Ll * Ll;
  float acc = 0.f;
  for (int u = 0; u < Ll; ++u) acc += g[(size_t)u * Ll + tid];
  ge[b * Ll + tid] = acc;
  int wave = tid >> 6, lane = tid & 63;
  for (int r = wave; r < Ll; r += 4) {
    const float* gr = g + (size_t)r * Ll;
    float p = gr[lane] + gr[64 + lane] + gr[128 + lane] + gr[192 + lane];
    #pragma unroll
    for (int m = 1; m < 64; m <<= 1) p += __shfl_xor(p, m);
    if (lane == 0) gu[b * Ll + r] = p;
  }
}

// indel gates: ug[n][row] = valid * sigmoid(enc_row . gate_w + gate_b). grid 2048 x 256
__global__ __launch_bounds__(256) void k_ug(
    const float* __restrict__ enc, const float* __restrict__ gw,
    const float* __restrict__ gb, const int* __restrict__ ulp,
    const int* __restrict__ elp, float* __restrict__ ug)
{
  int tid = threadIdx.x;
  int gr = blockIdx.x * 4 + (tid >> 6);
  int lane = tid & 63;
  int n = gr >> 8, row = gr & 255;
  int s = n & 1;
  const float* x = enc + (size_t)gr * Cd;
  float p = 0.f;
  #pragma unroll
  for (int t = 0; t < 4; ++t) p = fmaf(x[lane + 64 * t], gw[lane + 64 * t], p);
  #pragma unroll
  for (int m = 1; m < 64; m <<= 1) p += __shfl_xor(p, m);
  if (lane == 0) {
    int u_len = ulp[0], e_len = elp[0];
    int mylen = s ? e_len : u_len;
    int other = s ? u_len : e_len;
    bool valid = (row < mylen) && (other > 0);
    ug[gr] = valid ? (1.f / (1.f + expf(-(p + gb[0])))) : 0.f;
  }
}

// feature vector: sub(512) | indel(512) | oh(32) | he(1). grid (B,4) x 256
__global__ __launch_bounds__(256) void k_feats(
    const float* __restrict__ enc, const float* __restrict__ gu,
    const float* __restrict__ ge, const float* __restrict__ ug,
    const float* __restrict__ oh, const float* __restrict__ he,
    float* __restrict__ fv)
{
  int b = blockIdx.x, which = blockIdx.y, c = threadIdx.x;
  const float* x; const float* wv; int dst;
  if (which == 0)      { x = enc + (size_t)(b*2+0)*Ll*Cd; wv = gu + b*Ll;       dst = 0;   }
  else if (which == 1) { x = enc + (size_t)(b*2+1)*Ll*Cd; wv = ge + b*Ll;       dst = 256; }
  else if (which == 2) { x = enc + (size_t)(b*2+0)*Ll*Cd; wv = ug + (b*2+0)*Ll; dst = 512; }
  else                 { x = enc + (size_t)(b*2+1)*Ll*Cd; wv = ug + (b*2+1)*Ll; dst = 768; }
  float acc = 0.f;
  for (int r = 0; r < Ll; ++r) acc = fmaf(wv[r], x[(size_t)r * Cd + c], acc);
  fv[(size_t)b * Fd + dst + c] = acc;
  if (which == 0) {
    if (c < OHd) fv[(size_t)b * Fd + 1024 + c] = oh[b * OHd + c];
    if (c == 32) fv[(size_t)b * Fd + 1056] = he[b];
  }
}

// output head: LN(F) -> relu(@od_w+od_b) -> @ow_w+ow_b. grid B x 256
__global__ __launch_bounds__(256) void k_head(
    const float* __restrict__ fv, const float* __restrict__ on_s,
    const float* __restrict__ on_b, const float* __restrict__ od_w,
    const float* __restrict__ od_b, const float* __restrict__ ow_w,
    const float* __restrict__ ow_b, float* __restrict__ outp)
{
  __shared__ float fs[Fd];
  __shared__ float ys[OUTd];
  __shared__ float red[4];
  int b = blockIdx.x, tid = threadIdx.x;
  for (int i = tid; i < Fd; i += 256) fs[i] = fv[(size_t)b * Fd + i];
  __syncthreads();
  float part = 0.f;
  for (int i = tid; i < Fd; i += 256) part += fs[i];
  #pragma unroll
  for (int m = 1; m < 64; m <<= 1) part += __shfl_xor(part, m);
  if ((tid & 63) == 0) red[tid >> 6] = part;
  __syncthreads();
  float mu = (red[0] + red[1] + red[2] + red[3]) * (1.f / (float)Fd);
  __syncthreads();
  float p2 = 0.f;
  for (int i = tid; i < Fd; i += 256) { float d = fs[i] - mu; p2 = fmaf(d, d, p2); }
  #pragma unroll
  for (int m = 1; m < 64; m <<= 1) p2 += __shfl_xor(p2, m);
  if ((tid & 63) == 0) red[tid >> 6] = p2;
  __syncthreads();
  float rstd = rsqrtf((red[0] + red[1] + red[2] + red[3]) * (1.f / (float)Fd) + 1e-6f);
  __syncthreads();
  for (int i = tid; i < Fd; i += 256)
    fs[i] = on_s[i] * (fs[i] - mu) * rstd + on_b[i];
  __syncthreads();
  float acc = od_b[tid];
  for (int f = 0; f < Fd; ++f) acc = fmaf(fs[f], od_w[(size_t)f * OUTd + tid], acc);
  ys[tid] = fmaxf(acc, 0.f);
  __syncthreads();
  if (tid < 3) {
    float o = ow_b[tid];
    for (int i = 0; i < OUTd; ++i) o = fmaf(ys[i], ow_w[i * 3 + tid], o);
    outp[b * 3 + tid] = o;
  }
}

// =====================================================================
extern "C" void kernel_launch(void* const* d_in, const int* in_sizes, int n_in,
                              void* d_out, int out_size, void* d_ws, size_t ws_size,
                              hipStream_t stream)
{
  const float* u_in   = (const float*)d_in[0];
  const float* e_in   = (const float*)d_in[1];
  const float* bpp    = (const float*)d_in[2];
  const float* oh     = (const float*)d_in[3];
  const float* he     = (const float*)d_in[4];
  const int*   ulp    = (const int*)d_in[5];
  const int*   elp    = (const int*)d_in[6];
  const float* emb_w  = (const float*)d_in[7];
  const float* emb_b  = (const float*)d_in[8];
  const float* ca_wq  = (const float*)d_in[9];
  const float* ca_wq_b= (const float*)d_in[10];
  const float* ca_wk  = (const float*)d_in[11];
  const float* ca_wk_b= (const float*)d_in[12];
  const float* ca_wv  = (const float*)d_in[13];
  const float* ca_wv_b= (const float*)d_in[14];
  const float* ca_wo  = (const float*)d_in[15];
  const float* ca_wo_b= (const float*)d_in[16];
  const float* ca_bw  = (const float*)d_in[17];
  const float* ca_bb  = (const float*)d_in[18];
  const float* sa_wq  = (const float*)d_in[19];
  const float* sa_wq_b= (const float*)d_in[20];
  const float* sa_wk  = (const float*)d_in[21];
  const float* sa_wk_b= (const float*)d_in[22];
  const float* sa_wv  = (const float*)d_in[23];
  const float* sa_wv_b= (const float*)d_in[24];
  const float* sa_wo  = (const float*)d_in[25];
  const float* sa_wo_b= (const float*)d_in[26];
  const float* mi_w   = (const float*)d_in[27];
  const float* mi_b   = (const float*)d_in[28];
  const float* mo_w   = (const float*)d_in[29];
  const float* mo_b   = (const float*)d_in[30];
  const float* cn_s   = (const float*)d_in[31];
  const float* cn_b   = (const float*)d_in[32];
  const float* sn_s   = (const float*)d_in[33];
  const float* sn_b   = (const float*)d_in[34];
  const float* mn_s   = (const float*)d_in[35];
  const float* mn_b   = (const float*)d_in[36];
  const float* pair_w = (const float*)d_in[37];
  const float* pu_w   = (const float*)d_in[38];
  const float* pu_b   = (const float*)d_in[39];
  const float* so_bw  = (const float*)d_in[40];
  const float* so_bb  = (const float*)d_in[41];
  const float* so_w   = (const float*)d_in[42];
  const float* so_b   = (const float*)d_in[43];
  const float* gate_w = (const float*)d_in[44];
  const float* gate_b = (const float*)d_in[45];
  const float* on_s   = (const float*)d_in[46];
  const float* on_b   = (const float*)d_in[47];
  const float* od_w   = (const float*)d_in[48];
  const float* od_b   = (const float*)d_in[49];
  const float* ow_w   = (const float*)d_in[50];
  const float* ow_b   = (const float*)d_in[51];

  float* ws   = (float*)d_ws;
  float* enc  = ws + WS_ENC;
  float* pair = ws + WS_PAIR;
  float* big  = ws + WS_BIG;
  float* qb   = big;
  float* kb   = big + 2097152;
  float* vb   = big + 4194304;
  float* ob   = big + 6291456;
  float* hb   = big;           // mlp hidden reuses q/k/v/o region
  float* gate = big;           // final-stage gate reuses region
  float* sp   = ws + WS_SP;
  float* gu   = ws + WS_GU;
  float* ge   = ws + WS_GE;
  float* ug   = ws + WS_UG;
  float* fv   = ws + WS_FV;

  const float sc = 1.0f / sqrtf((float)Dd);

  k_embed<<<8192, 256, 0, stream>>>(u_in, e_in, emb_w, emb_b, ulp, elp, enc);
  k_pairinit<<<4096, 256, 0, stream>>>(bpp, pair);

  for (int it = 0; it < 8; ++it) {
    int wi = it & 3;
    size_t wcc = (size_t)wi * Cd * Cd;     // C*H*D == C*C
    // ---- cross attention ----
    k_gemm_qkv<<<dim3(4,4,96), 256, 0, stream>>>(enc,
        ca_wq + wcc, ca_wq_b + wi*Cd, ca_wk + wcc, ca_wk_b + wi*Cd,
        ca_wv + wcc, ca_wv_b + wi*Cd, qb, kb, vb, sc);
    k_attn<1><<<dim3(32,8), 256, 0, stream>>>(qb, kb, vb, ob, pair,
        ca_bw + wi, ca_bb + wi, ulp, elp);
    k_gemm_out<<<dim3(4,4,32), 256, 0, stream>>>(ob, ca_wo + wcc, ca_wo_b + wi*Cd, enc);
    k_ln<<<2048, 256, 0, stream>>>(enc, cn_s + wi*Cd, cn_b + wi*Cd);
    // ---- self attention ----
    k_gemm_qkv<<<dim3(4,4,96), 256, 0, stream>>>(enc,
        sa_wq + wcc, sa_wq_b + wi*Cd, sa_wk + wcc, sa_wk_b + wi*Cd,
        sa_wv + wcc, sa_wv_b + wi*Cd, qb, kb, vb, sc);
    k_attn<0><<<dim3(32,8), 256, 0, stream>>>(qb, kb, vb, ob, nullptr,
        nullptr, nullptr, ulp, elp);
    k_gemm_out<<<dim3(4,4,32), 256, 0, stream>>>(ob, sa_wo + wcc, sa_wo_b + wi*Cd, enc);
    k_ln<<<2048, 256, 0, stream>>>(enc, sn_s + wi*Cd, sn_b + wi*Cd);
    // ---- MLP ----
    k_gemm_mlpin<<<dim3(16,4,32), 256, 0, stream>>>(enc,
        mi_w + (size_t)wi*Cd*Md, mi_b + (size_t)wi*Md, hb);
    k_gemm_mlpout<<<dim3(4,4,32), 256, 0, stream>>>(hb,
        mo_w + (size_t)wi*Md*Cd, mo_b + wi*Cd, enc);
    k_ln<<<2048, 256, 0, stream>>>(enc, mn_s + wi*Cd, mn_b + wi*Cd);
    // ---- pair outer-product update ----
    k_proj32<<<1024, 256, 0, stream>>>(enc, pu_w + (size_t)wi*Cd*Pp, pu_b + wi*Pp, sp);
    k_pairop<0><<<dim3(4,4,Bb), 256, 0, stream>>>(sp, pair, nullptr,
        pair_w + wi, nullptr, ulp, elp);
  }

  // ---- outputs ----
  k_proj32<<<1024, 256, 0, stream>>>(enc, so_w, so_b, sp);
  k_pairop<1><<<dim3(4,4,Bb), 256, 0, stream>>>(sp, pair, gate, so_bw, so_bb, ulp, elp);
  k_sums<<<Bb, 256, 0, stream>>>(gate, gu, ge);
  k_ug<<<2048, 256, 0, stream>>>(enc, gate_w, gate_b, ulp, elp, ug);
  k_feats<<<dim3(Bb,4), 256, 0, stream>>>(enc, gu, ge, ug, oh, he, fv);
  k_head<<<Bb, 256, 0, stream>>>(fv, on_s, on_b, od_w, od_b, ow_w, ow_b, (float*)d_out);
}

// Round 4
// 4093.311 us; speedup vs baseline: 1.1974x; 1.1974x over previous
//
#include <hip/hip_runtime.h>
#include <math.h>

// ---- problem constants ----
#define Bb   16
#define Ll   256      // U = E
#define Cd   256
#define Hh   8
#define Dd   32
#define Md   1024
#define Pp   32
#define OUTd 256
#define OHd  32
#define FINd 5
#define Fd   1057     // 4*C + OH + 1
#define KS   4        // attention key splits
#define NEG_HUGE (-3.402823466e38f)

// ---- workspace layout (float offsets) ----
#define WS_ENC   0u           // 2B*L*C           = 2,097,152
#define WS_PAIR  2097152u     // B*L*L            = 1,048,576
#define WS_PAIRT 3145728u     // B*L*L (transpose)= 1,048,576
#define WS_BIG   4194304u     // 8,388,608 (q,k,v,o / mlp hidden / gate)
#define WS_PO    12582912u    // 2B*H*KS*L*D      = 8,388,608
#define WS_PML   20971520u    // 2B*H*KS*L*2      = 524,288
#define WS_SP    21495808u    // 2B*L*P           = 262,144
#define WS_GU    21757952u    // B*L
#define WS_GE    21762048u    // B*L
#define WS_UG    21766144u    // 2B*L
#define WS_FV    21774336u    // B*Fd

// =====================================================================
// GEMM core: C[64x64 tile] = alpha*(A@W + bias) (+relu) (+resid)
// =====================================================================
template<bool RELU, bool RESID>
__device__ __forceinline__ void gemm_core(
    const float* __restrict__ A, int lda,
    const float* __restrict__ W, int ldw,
    const float* __restrict__ bias,
    float* __restrict__ Cp, int ldc,
    const float* __restrict__ resid,
    int K, float alpha)
{
  __shared__ float As[32][68];
  __shared__ float Bs[32][68];
  const int tid  = threadIdx.x;
  const int row0 = blockIdx.y * 64;
  const int col0 = blockIdx.x * 64;
  const int tr = tid >> 4, tc = tid & 15;
  float acc[4][4] = {};
  for (int k0 = 0; k0 < K; k0 += 32) {
    #pragma unroll
    for (int t = 0; t < 8; ++t) {
      int idx = t * 256 + tid;
      int ra = idx >> 5, ka = idx & 31;
      As[ka][ra] = A[(size_t)(row0 + ra) * lda + (k0 + ka)];
      int kb = idx >> 6, cb = idx & 63;
      Bs[kb][cb] = W[(size_t)(k0 + kb) * ldw + (col0 + cb)];
    }
    __syncthreads();
    #pragma unroll
    for (int kk = 0; kk < 32; ++kk) {
      float4 av = *(const float4*)&As[kk][tr * 4];
      float4 bv = *(const float4*)&Bs[kk][tc * 4];
      float aa[4] = {av.x, av.y, av.z, av.w};
      float bb[4] = {bv.x, bv.y, bv.z, bv.w};
      #pragma unroll
      for (int i = 0; i < 4; ++i)
        #pragma unroll
        for (int j = 0; j < 4; ++j)
          acc[i][j] = fmaf(aa[i], bb[j], acc[i][j]);
    }
    __syncthreads();
  }
  float4 bv4 = *(const float4*)&bias[col0 + tc * 4];
  float bb[4] = {bv4.x, bv4.y, bv4.z, bv4.w};
  #pragma unroll
  for (int i = 0; i < 4; ++i) {
    int r = row0 + tr * 4 + i;
    float v[4];
    #pragma unroll
    for (int j = 0; j < 4; ++j) {
      v[j] = alpha * (acc[i][j] + bb[j]);
      if (RELU) v[j] = fmaxf(v[j], 0.f);
    }
    if (RESID) {
      float4 rv = *(const float4*)&resid[(size_t)r * ldc + col0 + tc * 4];
      v[0] += rv.x; v[1] += rv.y; v[2] += rv.z; v[3] += rv.w;
    }
    float4 ov = {v[0], v[1], v[2], v[3]};
    *(float4*)&Cp[(size_t)r * ldc + col0 + tc * 4] = ov;
  }
}

__global__ __launch_bounds__(256) void k_gemm_qkv(
    const float* __restrict__ enc,
    const float* __restrict__ wq, const float* __restrict__ bq,
    const float* __restrict__ wk, const float* __restrict__ bk,
    const float* __restrict__ wv, const float* __restrict__ bv,
    float* __restrict__ q, float* __restrict__ k, float* __restrict__ v, float scale)
{
  int z = blockIdx.z;
  int n = z / 3, pr = z % 3;
  const float* W; const float* bias; float* out; float alpha = 1.f;
  if (pr == 0)      { W = wq; bias = bq; out = q; alpha = scale; }
  else if (pr == 1) { W = wk; bias = bk; out = k; }
  else              { W = wv; bias = bv; out = v; }
  size_t off = (size_t)n * Ll * Cd;
  gemm_core<false,false>(enc + off, Cd, W, Cd, bias, out + off, Cd, nullptr, Cd, alpha);
}

__global__ __launch_bounds__(256) void k_gemm_out(
    const float* __restrict__ ob, const float* __restrict__ wo,
    const float* __restrict__ bo, float* __restrict__ enc)
{
  size_t off = (size_t)blockIdx.z * Ll * Cd;
  gemm_core<false,true>(ob + off, Cd, wo, Cd, bo, enc + off, Cd, enc + off, Cd, 1.f);
}

__global__ __launch_bounds__(256) void k_gemm_mlpin(
    const float* __restrict__ enc, const float* __restrict__ win,
    const float* __restrict__ bin, float* __restrict__ h)
{
  size_t offa = (size_t)blockIdx.z * Ll * Cd;
  size_t offc = (size_t)blockIdx.z * Ll * Md;
  gemm_core<true,false>(enc + offa, Cd, win, Md, bin, h + offc, Md, nullptr, Cd, 1.f);
}

__global__ __launch_bounds__(256) void k_gemm_mlpout(
    const float* __restrict__ h, const float* __restrict__ wout,
    const float* __restrict__ bout, float* __restrict__ enc)
{
  size_t offa = (size_t)blockIdx.z * Ll * Md;
  size_t offc = (size_t)blockIdx.z * Ll * Cd;
  gemm_core<false,true>(h + offa, Md, wout, Cd, bout, enc + offc, Cd, enc + offc, Md, 1.f);
}

// =====================================================================
// LayerNorm in-place over C=256, wave per row.
// =====================================================================
__global__ __launch_bounds__(256) void k_ln(float* __restrict__ enc,
    const float* __restrict__ s, const float* __restrict__ b2)
{
  int tid = threadIdx.x;
  int r = blockIdx.x * 4 + (tid >> 6);
  int lane = tid & 63;
  float* row = enc + (size_t)r * Cd;
  float4 v = ((float4*)row)[lane];
  float p = v.x + v.y + v.z + v.w;
  #pragma unroll
  for (int m = 1; m < 64; m <<= 1) p += __shfl_xor(p, m);
  float mu = p * (1.f / 256.f);
  float dx = v.x - mu, dy = v.y - mu, dz = v.z - mu, dw = v.w - mu;
  float q = dx*dx + dy*dy + dz*dz + dw*dw;
  #pragma unroll
  for (int m = 1; m < 64; m <<= 1) q += __shfl_xor(q, m);
  float rstd = rsqrtf(q * (1.f / 256.f) + 1e-6f);
  float4 sv = ((const float4*)s)[lane];
  float4 bv = ((const float4*)b2)[lane];
  v.x = sv.x * dx * rstd + bv.x;
  v.y = sv.y * dy * rstd + bv.y;
  v.z = sv.z * dz * rstd + bv.z;
  v.w = sv.w * dw * rstd + bv.w;
  ((float4*)row)[lane] = v;
}

// =====================================================================
// Attention, key-split flash style.
// part: grid (2B, H, KS), 256 thr; thread = query row; 64 keys per block.
// Writes unnormalized partial o + (m,l) per split.
// =====================================================================
template<int CROSS>
__global__ __launch_bounds__(256) void k_attn_part(
    const float* __restrict__ qb, const float* __restrict__ kb,
    const float* __restrict__ vb,
    const float* __restrict__ pair, const float* __restrict__ pairT,
    const float* __restrict__ bw_p, const float* __restrict__ bb_p,
    const int* __restrict__ ulp, const int* __restrict__ elp,
    float* __restrict__ po, float* __restrict__ pml)
{
  __shared__ float ks_[32][32];
  __shared__ float vs_[32][32];
  const int tid = threadIdx.x;
  const int n = blockIdx.x, h = blockIdx.y, kspl = blockIdx.z;
  const int b = n >> 1, s = n & 1;
  const int u_len = ulp[0], e_len = elp[0];
  const int nkv = CROSS ? (n ^ 1) : n;
  const int qlen  = s ? e_len : u_len;
  const int kvlen = CROSS ? (s ? u_len : e_len) : qlen;
  const int k0base = kspl * 64;
  const float* qp = qb + (size_t)n   * Ll * Cd + h * Dd;
  const float* kp = kb + (size_t)nkv * Ll * Cd + h * Dd;
  const float* vp = vb + (size_t)nkv * Ll * Cd + h * Dd;
  float bw = 0.f, bbias = 0.f;
  const float* prow = nullptr;
  if (CROSS) {
    bw = bw_p[0]; bbias = bb_p[0];
    prow = (s == 0 ? pair : pairT) + ((size_t)b * Ll + tid) * Ll;
  }

  float qv[32];
  {
    const float4* q4 = (const float4*)(qp + (size_t)tid * Cd);
    #pragma unroll
    for (int t = 0; t < 8; ++t) {
      float4 x = q4[t];
      qv[4*t] = x.x; qv[4*t+1] = x.y; qv[4*t+2] = x.z; qv[4*t+3] = x.w;
    }
  }
  const bool qvalid = tid < qlen;
  float m = NEG_HUGE, l = 0.f;
  float oa[32];
  #pragma unroll
  for (int d = 0; d < 32; ++d) oa[d] = 0.f;

  #pragma unroll
  for (int cc = 0; cc < 2; ++cc) {
    const int c0 = k0base + cc * 32;
    __syncthreads();
    #pragma unroll
    for (int t = 0; t < 4; ++t) {
      int idx = t * 256 + tid;
      int r = idx >> 5, d = idx & 31;
      ks_[r][d] = kp[(size_t)(c0 + r) * Cd + d];
      vs_[r][d] = vp[(size_t)(c0 + r) * Cd + d];
    }
    float pr[32];
    if (CROSS) {
      const float4* p4 = (const float4*)(prow + c0);
      #pragma unroll
      for (int t = 0; t < 8; ++t) {
        float4 x = p4[t];
        pr[4*t] = x.x; pr[4*t+1] = x.y; pr[4*t+2] = x.z; pr[4*t+3] = x.w;
      }
    }
    __syncthreads();
    #pragma unroll 2
    for (int ec = 0; ec < 32; ++ec) {
      int e = c0 + ec;
      float s0 = 0.f, s1 = 0.f, s2 = 0.f, s3 = 0.f;
      const float4* kr = (const float4*)&ks_[ec][0];
      #pragma unroll
      for (int t = 0; t < 8; ++t) {
        float4 kx = kr[t];
        s0 = fmaf(qv[4*t],   kx.x, s0);
        s1 = fmaf(qv[4*t+1], kx.y, s1);
        s2 = fmaf(qv[4*t+2], kx.z, s2);
        s3 = fmaf(qv[4*t+3], kx.w, s3);
      }
      float sd = (s0 + s1) + (s2 + s3);
      if (CROSS) sd = fmaf(bw, pr[ec], sd + bbias);
      bool valid = qvalid && (e < kvlen);
      float sv = valid ? sd : NEG_HUGE;
      if (sv > m) {
        float corr = __expf(m - sv);
        l *= corr;
        #pragma unroll
        for (int d = 0; d < 32; ++d) oa[d] *= corr;
        m = sv;
      }
      float p = __expf(sv - m);
      l += p;
      const float4* vr = (const float4*)&vs_[ec][0];
      #pragma unroll
      for (int t = 0; t < 8; ++t) {
        float4 vx = vr[t];
        oa[4*t]   = fmaf(p, vx.x, oa[4*t]);
        oa[4*t+1] = fmaf(p, vx.y, oa[4*t+1]);
        oa[4*t+2] = fmaf(p, vx.z, oa[4*t+2]);
        oa[4*t+3] = fmaf(p, vx.w, oa[4*t+3]);
      }
    }
  }
  size_t pidx = (((size_t)(n * Hh + h) * KS + kspl) * Ll + tid);
  float* pop = po + pidx * Dd;
  #pragma unroll
  for (int t = 0; t < 8; ++t) {
    float4 x = {oa[4*t], oa[4*t+1], oa[4*t+2], oa[4*t+3]};
    ((float4*)pop)[t] = x;
  }
  pml[pidx * 2]     = m;
  pml[pidx * 2 + 1] = l;
}

// merge: grid (2B, H), 256 thr; thread = query row.
template<int CROSS>
__global__ __launch_bounds__(256) void k_attn_merge(
    const float* __restrict__ po, const float* __restrict__ pml,
    float* __restrict__ ob,
    const int* __restrict__ ulp, const int* __restrict__ elp)
{
  const int tid = threadIdx.x;
  const int n = blockIdx.x, h = blockIdx.y;
  const int s = n & 1;
  const int qlen = s ? elp[0] : ulp[0];
  size_t base = ((size_t)(n * Hh + h) * KS) * Ll + tid;
  float ms[KS], ls[KS];
  #pragma unroll
  for (int i = 0; i < KS; ++i) {
    ms[i] = pml[(base + (size_t)i * Ll) * 2];
    ls[i] = pml[(base + (size_t)i * Ll) * 2 + 1];
  }
  float M = ms[0];
  #pragma unroll
  for (int i = 1; i < KS; ++i) M = fmaxf(M, ms[i]);
  float w[KS]; float L = 0.f;
  #pragma unroll
  for (int i = 0; i < KS; ++i) { w[i] = __expf(ms[i] - M); L += ls[i] * w[i]; }
  float oa[32];
  #pragma unroll
  for (int d = 0; d < 32; ++d) oa[d] = 0.f;
  #pragma unroll
  for (int i = 0; i < KS; ++i) {
    const float4* p4 = (const float4*)(po + (base + (size_t)i * Ll) * Dd);
    float wi = w[i];
    #pragma unroll
    for (int t = 0; t < 8; ++t) {
      float4 x = p4[t];
      oa[4*t]   = fmaf(wi, x.x, oa[4*t]);
      oa[4*t+1] = fmaf(wi, x.y, oa[4*t+1]);
      oa[4*t+2] = fmaf(wi, x.z, oa[4*t+2]);
      oa[4*t+3] = fmaf(wi, x.w, oa[4*t+3]);
    }
  }
  float om = 1.f / L;
  if (CROSS && tid >= qlen) om = 0.f;   // cross: ue_m post-mask zeroes invalid rows
  float* op = ob + ((size_t)n * Ll + tid) * Cd + h * Dd;
  #pragma unroll
  for (int t = 0; t < 8; ++t) {
    float4 x = {oa[4*t] * om, oa[4*t+1] * om, oa[4*t+2] * om, oa[4*t+3] * om};
    ((float4*)op)[t] = x;
  }
}

// =====================================================================
// Embedding + PE + mask. grid 8192 x 256
// =====================================================================
__global__ __launch_bounds__(256) void k_embed(
    const float* __restrict__ u_in, const float* __restrict__ e_in,
    const float* __restrict__ emb_w, const float* __restrict__ emb_b,
    const int* __restrict__ ulp, const int* __restrict__ elp,
    float* __restrict__ enc)
{
  int gid = blockIdx.x * 256 + threadIdx.x;
  int c = gid & 255;
  int row = (gid >> 8) & 255;
  int n = gid >> 16;
  int b = n >> 1, s = n & 1;
  const float* x = (s ? e_in : u_in) + ((size_t)b * Ll + row) * FINd;
  float acc = emb_b[c];
  #pragma unroll
  for (int f = 0; f < FINd; ++f) acc = fmaf(x[f], emb_w[f * Cd + c], acc);
  const float k2 = 0.051902826f;  // log2(10000)/256
  float dv = exp2f(-k2 * (float)(2 * (c >> 1)));
  float ang = (float)row * dv;
  float pe = ((c & 1) == 0) ? sinf(ang) : cosf(ang);
  int len = s ? elp[0] : ulp[0];
  enc[gid] = (row < len) ? (acc + pe) : 0.f;
}

// pair = logit(bpp); also writes pairT. grid (B,8,8), 32x32 tile per block.
__global__ __launch_bounds__(256) void k_pairinit(
    const float* __restrict__ bpp, float* __restrict__ pair, float* __restrict__ pairT)
{
  __shared__ float tile[32][33];
  const int tid = threadIdx.x;
  const int b = blockIdx.x;
  const int u0 = blockIdx.y * 32, e0 = blockIdx.z * 32;
  #pragma unroll
  for (int t = 0; t < 4; ++t) {
    int idx = t * 256 + tid;
    int r = idx >> 5, c = idx & 31;
    float v = bpp[((size_t)b * Ll + u0 + r) * Ll + e0 + c];
    float val = logf(v + 1e-3f) - logf(1.f - v + 1e-3f);
    pair[((size_t)b * Ll + u0 + r) * Ll + e0 + c] = val;
    tile[r][c] = val;
  }
  __syncthreads();
  #pragma unroll
  for (int t = 0; t < 4; ++t) {
    int idx = t * 256 + tid;
    int r = idx >> 5, c = idx & 31;
    pairT[((size_t)b * Ll + e0 + r) * Ll + u0 + c] = tile[c][r];
  }
}

// proj to P=32 columns. grid 1024 x 256
__global__ __launch_bounds__(256) void k_proj32(
    const float* __restrict__ enc, const float* __restrict__ Wp,
    const float* __restrict__ bp, float* __restrict__ sp)
{
  int gid = blockIdx.x * 256 + threadIdx.x;
  int p = gid & 31;
  int grow = gid >> 5;
  const float4* x4 = (const float4*)(enc + (size_t)grow * Cd);
  float acc = bp[p];
  for (int c4 = 0; c4 < 64; ++c4) {
    float4 xv = x4[c4];
    int cb = c4 * 4;
    acc = fmaf(xv.x, Wp[(cb    ) * Pp + p], acc);
    acc = fmaf(xv.y, Wp[(cb + 1) * Pp + p], acc);
    acc = fmaf(xv.z, Wp[(cb + 2) * Pp + p], acc);
    acc = fmaf(xv.w, Wp[(cb + 3) * Pp + p], acc);
  }
  sp[(size_t)grow * Pp + p] = acc;
}

// MODE 0: pair += w * mask * (su@se^T)   (also maintains pairT)
// MODE 1: gate = mask ? sigmoid(w*pair + b + su@se^T) : 0
template<int MODE>
__global__ __launch_bounds__(256) void k_pairop(
    const float* __restrict__ sp, float* __restrict__ pair, float* __restrict__ pairT,
    float* __restrict__ gate,
    const float* __restrict__ w_p, const float* __restrict__ b_p,
    const int* __restrict__ ulp, const int* __restrict__ elp)
{
  __shared__ float su[32][36];
  __shared__ float se[32][36];
  const int tid = threadIdx.x;
  const int b = blockIdx.z;
  const int u0 = blockIdx.y * 64, e0 = blockIdx.x * 64;
  const float* spu = sp + ((size_t)(b * 2 + 0) * Ll + u0) * Pp;
  const float* spe = sp + ((size_t)(b * 2 + 1) * Ll + e0) * Pp;
  #pragma unroll
  for (int t = 0; t < 8; ++t) {
    int idx = t * 256 + tid;
    int r = idx >> 5, p = idx & 31;
    su[p][r] = spu[r * Pp + p];
    se[p][r] = spe[r * Pp + p];
  }
  __syncthreads();
  const int tr = tid >> 4, tc = tid & 15;
  float acc[4][4] = {};
  #pragma unroll
  for (int p = 0; p < 32; ++p) {
    float4 av = *(const float4*)&su[p][tr * 4];
    float4 bv = *(const float4*)&se[p][tc * 4];
    float aa[4] = {av.x, av.y, av.z, av.w};
    float bb[4] = {bv.x, bv.y, bv.z, bv.w};
    #pragma unroll
    for (int i = 0; i < 4; ++i)
      #pragma unroll
      for (int j = 0; j < 4; ++j)
        acc[i][j] = fmaf(aa[i], bb[j], acc[i][j]);
  }
  const int u_len = ulp[0], e_len = elp[0];
  const float w = w_p[0];
  const float bb2 = MODE ? b_p[0] : 0.f;
  float res[4][4];
  #pragma unroll
  for (int i = 0; i < 4; ++i) {
    int u = u0 + tr * 4 + i;
    bool uval = u < u_len;
    size_t off = ((size_t)b * Ll + u) * Ll + e0 + tc * 4;
    float4 prv = *(const float4*)&pair[off];
    float pv[4] = {prv.x, prv.y, prv.z, prv.w};
    #pragma unroll
    for (int j = 0; j < 4; ++j) {
      bool valid = uval && ((e0 + tc * 4 + j) < e_len);
      if (MODE == 0) {
        res[i][j] = pv[j] + w * (valid ? acc[i][j] : 0.f);
      } else {
        float z = fmaf(w, pv[j], bb2) + acc[i][j];
        res[i][j] = valid ? (1.f / (1.f + expf(-z))) : 0.f;
      }
    }
    float4 ov = {res[i][0], res[i][1], res[i][2], res[i][3]};
    if (MODE == 0) *(float4*)&pair[off] = ov;
    else           *(float4*)&gate[off] = ov;
  }
  if (MODE == 0) {
    #pragma unroll
    for (int j = 0; j < 4; ++j) {
      size_t offt = ((size_t)b * Ll + e0 + tc * 4 + j) * Ll + u0 + tr * 4;
      float4 tv = {res[0][j], res[1][j], res[2][j], res[3][j]};
      *(float4*)&pairT[offt] = tv;
    }
  }
}

// gate row/col sums. grid B x 256
__global__ __launch_bounds__(256) void k_sums(
    const float* __restrict__ gate, float* __restrict__ gu, float* __restrict__ ge)
{
  int b = blockIdx.x, tid = threadIdx.x;
  const float* g = gate + (size_t)b * Ll * Ll;
  float acc = 0.f;
  for (int u = 0; u < Ll; ++u) acc += g[(size_t)u * Ll + tid];
  ge[b * Ll + tid] = acc;
  int wave = tid >> 6, lane = tid & 63;
  for (int r = wave; r < Ll; r += 4) {
    const float* gr = g + (size_t)r * Ll;
    float p = gr[lane] + gr[64 + lane] + gr[128 + lane] + gr[192 + lane];
    #pragma unroll
    for (int m = 1; m < 64; m <<= 1) p += __shfl_xor(p, m);
    if (lane == 0) gu[b * Ll + r] = p;
  }
}

// indel gates. grid 2048 x 256
__global__ __launch_bounds__(256) void k_ug(
    const float* __restrict__ enc, const float* __restrict__ gw,
    const float* __restrict__ gb, const int* __restrict__ ulp,
    const int* __restrict__ elp, float* __restrict__ ug)
{
  int tid = threadIdx.x;
  int gr = blockIdx.x * 4 + (tid >> 6);
  int lane = tid & 63;
  int n = gr >> 8, row = gr & 255;
  int s = n & 1;
  const float* x = enc + (size_t)gr * Cd;
  float p = 0.f;
  #pragma unroll
  for (int t = 0; t < 4; ++t) p = fmaf(x[lane + 64 * t], gw[lane + 64 * t], p);
  #pragma unroll
  for (int m = 1; m < 64; m <<= 1) p += __shfl_xor(p, m);
  if (lane == 0) {
    int u_len = ulp[0], e_len = elp[0];
    int mylen = s ? e_len : u_len;
    int other = s ? u_len : e_len;
    bool valid = (row < mylen) && (other > 0);
    ug[gr] = valid ? (1.f / (1.f + expf(-(p + gb[0])))) : 0.f;
  }
}

// feature vector. grid (B,4) x 256
__global__ __launch_bounds__(256) void k_feats(
    const float* __restrict__ enc, const float* __restrict__ gu,
    const float* __restrict__ ge, const float* __restrict__ ug,
    const float* __restrict__ oh, const float* __restrict__ he,
    float* __restrict__ fv)
{
  int b = blockIdx.x, which = blockIdx.y, c = threadIdx.x;
  const float* x; const float* wv; int dst;
  if (which == 0)      { x = enc + (size_t)(b*2+0)*Ll*Cd; wv = gu + b*Ll;       dst = 0;   }
  else if (which == 1) { x = enc + (size_t)(b*2+1)*Ll*Cd; wv = ge + b*Ll;       dst = 256; }
  else if (which == 2) { x = enc + (size_t)(b*2+0)*Ll*Cd; wv = ug + (b*2+0)*Ll; dst = 512; }
  else                 { x = enc + (size_t)(b*2+1)*Ll*Cd; wv = ug + (b*2+1)*Ll; dst = 768; }
  float acc = 0.f;
  for (int r = 0; r < Ll; ++r) acc = fmaf(wv[r], x[(size_t)r * Cd + c], acc);
  fv[(size_t)b * Fd + dst + c] = acc;
  if (which == 0) {
    if (c < OHd) fv[(size_t)b * Fd + 1024 + c] = oh[b * OHd + c];
    if (c == 32) fv[(size_t)b * Fd + 1056] = he[b];
  }
}

// output head. grid B x 256
__global__ __launch_bounds__(256) void k_head(
    const float* __restrict__ fv, const float* __restrict__ on_s,
    const float* __restrict__ on_b, const float* __restrict__ od_w,
    const float* __restrict__ od_b, const float* __restrict__ ow_w,
    const float* __restrict__ ow_b, float* __restrict__ outp)
{
  __shared__ float fs[Fd];
  __shared__ float ys[OUTd];
  __shared__ float red[4];
  int b = blockIdx.x, tid = threadIdx.x;
  for (int i = tid; i < Fd; i += 256) fs[i] = fv[(size_t)b * Fd + i];
  __syncthreads();
  float part = 0.f;
  for (int i = tid; i < Fd; i += 256) part += fs[i];
  #pragma unroll
  for (int m = 1; m < 64; m <<= 1) part += __shfl_xor(part, m);
  if ((tid & 63) == 0) red[tid >> 6] = part;
  __syncthreads();
  float mu = (red[0] + red[1] + red[2] + red[3]) * (1.f / (float)Fd);
  __syncthreads();
  float p2 = 0.f;
  for (int i = tid; i < Fd; i += 256) { float d = fs[i] - mu; p2 = fmaf(d, d, p2); }
  #pragma unroll
  for (int m = 1; m < 64; m <<= 1) p2 += __shfl_xor(p2, m);
  if ((tid & 63) == 0) red[tid >> 6] = p2;
  __syncthreads();
  float rstd = rsqrtf((red[0] + red[1] + red[2] + red[3]) * (1.f / (float)Fd) + 1e-6f);
  __syncthreads();
  for (int i = tid; i < Fd; i += 256)
    fs[i] = on_s[i] * (fs[i] - mu) * rstd + on_b[i];
  __syncthreads();
  float acc = od_b[tid];
  for (int f = 0; f < Fd; ++f) acc = fmaf(fs[f], od_w[(size_t)f * OUTd + tid], acc);
  ys[tid] = fmaxf(acc, 0.f);
  __syncthreads();
  if (tid < 3) {
    float o = ow_b[tid];
    for (int i = 0; i < OUTd; ++i) o = fmaf(ys[i], ow_w[i * 3 + tid], o);
    outp[b * 3 + tid] = o;
  }
}

// =====================================================================
extern "C" void kernel_launch(void* const* d_in, const int* in_sizes, int n_in,
                              void* d_out, int out_size, void* d_ws, size_t ws_size,
                              hipStream_t stream)
{
  const float* u_in   = (const float*)d_in[0];
  const float* e_in   = (const float*)d_in[1];
  const float* bpp    = (const float*)d_in[2];
  const float* oh     = (const float*)d_in[3];
  const float* he     = (const float*)d_in[4];
  const int*   ulp    = (const int*)d_in[5];
  const int*   elp    = (const int*)d_in[6];
  const float* emb_w  = (const float*)d_in[7];
  const float* emb_b  = (const float*)d_in[8];
  const float* ca_wq  = (const float*)d_in[9];
  const float* ca_wq_b= (const float*)d_in[10];
  const float* ca_wk  = (const float*)d_in[11];
  const float* ca_wk_b= (const float*)d_in[12];
  const float* ca_wv  = (const float*)d_in[13];
  const float* ca_wv_b= (const float*)d_in[14];
  const float* ca_wo  = (const float*)d_in[15];
  const float* ca_wo_b= (const float*)d_in[16];
  const float* ca_bw  = (const float*)d_in[17];
  const float* ca_bb  = (const float*)d_in[18];
  const float* sa_wq  = (const float*)d_in[19];
  const float* sa_wq_b= (const float*)d_in[20];
  const float* sa_wk  = (const float*)d_in[21];
  const float* sa_wk_b= (const float*)d_in[22];
  const float* sa_wv  = (const float*)d_in[23];
  const float* sa_wv_b= (const float*)d_in[24];
  const float* sa_wo  = (const float*)d_in[25];
  const float* sa_wo_b= (const float*)d_in[26];
  const float* mi_w   = (const float*)d_in[27];
  const float* mi_b   = (const float*)d_in[28];
  const float* mo_w   = (const float*)d_in[29];
  const float* mo_b   = (const float*)d_in[30];
  const float* cn_s   = (const float*)d_in[31];
  const float* cn_b   = (const float*)d_in[32];
  const float* sn_s   = (const float*)d_in[33];
  const float* sn_b   = (const float*)d_in[34];
  const float* mn_s   = (const float*)d_in[35];
  const float* mn_b   = (const float*)d_in[36];
  const float* pair_w = (const float*)d_in[37];
  const float* pu_w   = (const float*)d_in[38];
  const float* pu_b   = (const float*)d_in[39];
  const float* so_bw  = (const float*)d_in[40];
  const float* so_bb  = (const float*)d_in[41];
  const float* so_w   = (const float*)d_in[42];
  const float* so_b   = (const float*)d_in[43];
  const float* gate_w = (const float*)d_in[44];
  const float* gate_b = (const float*)d_in[45];
  const float* on_s   = (const float*)d_in[46];
  const float* on_b   = (const float*)d_in[47];
  const float* od_w   = (const float*)d_in[48];
  const float* od_b   = (const float*)d_in[49];
  const float* ow_w   = (const float*)d_in[50];
  const float* ow_b   = (const float*)d_in[51];

  float* ws    = (float*)d_ws;
  float* enc   = ws + WS_ENC;
  float* pair  = ws + WS_PAIR;
  float* pairT = ws + WS_PAIRT;
  float* big   = ws + WS_BIG;
  float* qb    = big;
  float* kb    = big + 2097152;
  float* vb    = big + 4194304;
  float* ob    = big + 6291456;
  float* hb    = big;           // mlp hidden reuses q/k/v/o region
  float* gate  = big;           // final-stage gate reuses region
  float* po    = ws + WS_PO;
  float* pml   = ws + WS_PML;
  float* sp    = ws + WS_SP;
  float* gu    = ws + WS_GU;
  float* ge    = ws + WS_GE;
  float* ug    = ws + WS_UG;
  float* fv    = ws + WS_FV;

  const float sc = 1.0f / sqrtf((float)Dd);

  k_embed<<<8192, 256, 0, stream>>>(u_in, e_in, emb_w, emb_b, ulp, elp, enc);
  k_pairinit<<<dim3(Bb,8,8), 256, 0, stream>>>(bpp, pair, pairT);

  for (int it = 0; it < 8; ++it) {
    int wi = it & 3;
    size_t wcc = (size_t)wi * Cd * Cd;     // C*H*D == C*C
    // ---- cross attention ----
    k_gemm_qkv<<<dim3(4,4,96), 256, 0, stream>>>(enc,
        ca_wq + wcc, ca_wq_b + wi*Cd, ca_wk + wcc, ca_wk_b + wi*Cd,
        ca_wv + wcc, ca_wv_b + wi*Cd, qb, kb, vb, sc);
    k_attn_part<1><<<dim3(32,Hh,KS), 256, 0, stream>>>(qb, kb, vb, pair, pairT,
        ca_bw + wi, ca_bb + wi, ulp, elp, po, pml);
    k_attn_merge<1><<<dim3(32,Hh), 256, 0, stream>>>(po, pml, ob, ulp, elp);
    k_gemm_out<<<dim3(4,4,32), 256, 0, stream>>>(ob, ca_wo + wcc, ca_wo_b + wi*Cd, enc);
    k_ln<<<2048, 256, 0, stream>>>(enc, cn_s + wi*Cd, cn_b + wi*Cd);
    // ---- self attention ----
    k_gemm_qkv<<<dim3(4,4,96), 256, 0, stream>>>(enc,
        sa_wq + wcc, sa_wq_b + wi*Cd, sa_wk + wcc, sa_wk_b + wi*Cd,
        sa_wv + wcc, sa_wv_b + wi*Cd, qb, kb, vb, sc);
    k_attn_part<0><<<dim3(32,Hh,KS), 256, 0, stream>>>(qb, kb, vb, nullptr, nullptr,
        nullptr, nullptr, ulp, elp, po, pml);
    k_attn_merge<0><<<dim3(32,Hh), 256, 0, stream>>>(po, pml, ob, ulp, elp);
    k_gemm_out<<<dim3(4,4,32), 256, 0, stream>>>(ob, sa_wo + wcc, sa_wo_b + wi*Cd, enc);
    k_ln<<<2048, 256, 0, stream>>>(enc, sn_s + wi*Cd, sn_b + wi*Cd);
    // ---- MLP ----
    k_gemm_mlpin<<<dim3(16,4,32), 256, 0, stream>>>(enc,
        mi_w + (size_t)wi*Cd*Md, mi_b + (size_t)wi*Md, hb);
    k_gemm_mlpout<<<dim3(4,4,32), 256, 0, stream>>>(hb,
        mo_w + (size_t)wi*Md*Cd, mo_b + wi*Cd, enc);
    k_ln<<<2048, 256, 0, stream>>>(enc, mn_s + wi*Cd, mn_b + wi*Cd);
    // ---- pair outer-product update (maintains pair AND pairT) ----
    k_proj32<<<1024, 256, 0, stream>>>(enc, pu_w + (size_t)wi*Cd*Pp, pu_b + wi*Pp, sp);
    k_pairop<0><<<dim3(4,4,Bb), 256, 0, stream>>>(sp, pair, pairT, nullptr,
        pair_w + wi, nullptr, ulp, elp);
  }

  // ---- outputs ----
  k_proj32<<<1024, 256, 0, stream>>>(enc, so_w, so_b, sp);
  k_pairop<1><<<dim3(4,4,Bb), 256, 0, stream>>>(sp, pair, pairT, gate, so_bw, so_bb, ulp, elp);
  k_sums<<<Bb, 256, 0, stream>>>(gate, gu, ge);
  k_ug<<<2048, 256, 0, stream>>>(enc, gate_w, gate_b, ulp, elp, ug);
  k_feats<<<dim3(Bb,4), 256, 0, stream>>>(enc, gu, ge, ug, oh, he, fv);
  k_head<<<Bb, 256, 0, stream>>>(fv, on_s, on_b, od_w, od_b, ow_w, ow_b, (float*)d_out);
}

// Round 5
// 2922.612 us; speedup vs baseline: 1.6770x; 1.4006x over previous
//
#include <hip/hip_runtime.h>
#include <math.h>

// ---- problem constants ----
#define Bb   16
#define Ll   256      // U = E
#define Cd   256
#define Hh   8
#define Dd   32
#define Md   1024
#define Pp   32
#define OUTd 256
#define OHd  32
#define FINd 5
#define Fd   1057     // 4*C + OH + 1
#define KS   4        // attention key splits
#define NEG_HUGE (-3.402823466e38f)

// ---- workspace layout (float offsets) ----
#define WS_ENC   0u           // 2B*L*C           = 2,097,152
#define WS_PAIR  2097152u     // B*L*L            = 1,048,576
#define WS_PAIRT 3145728u     // B*L*L (transpose)= 1,048,576
#define WS_BIG   4194304u     // 8,388,608 (q,k,v,o / mlp hidden / gate)
#define WS_PO    12582912u    // 2B*H*KS*L*D      = 8,388,608
#define WS_PML   20971520u    // 2B*H*KS*L*2      = 524,288
#define WS_SP    21495808u    // 2B*L*P           = 262,144
#define WS_GU    21757952u    // B*L
#define WS_GE    21762048u    // B*L
#define WS_UG    21766144u    // 2B*L
#define WS_FV    21774336u    // B*Fd

typedef __attribute__((ext_vector_type(8))) short short8v;
typedef __attribute__((ext_vector_type(4))) float f32x4;

__device__ __forceinline__ unsigned short bf_rne(float x) {
  unsigned u = __float_as_uint(x);
  return (unsigned short)((u + 0x7FFFu + ((u >> 16) & 1u)) >> 16);
}

// =====================================================================
// Split-bf16 MFMA GEMM core.
// C[64x64 tile] = alpha*(A@W + bias) (+relu) (+resid)
// A: [M][lda] f32 row-major (k contiguous), W: [K][ldw] f32 row-major.
// Each f32 split hi/lo bf16; product = hi*hi + hi*lo + lo*hi (3 MFMA).
// 256 thr = 4 waves, wave tile 32x32, BK=32.
// LDS planes [64][40] bf16: pitch 80B (16B-aligned b128, ~2-way banks).
// =====================================================================
template<bool RELU, bool RESID>
__device__ __forceinline__ void mfma_core(
    const float* __restrict__ A, int lda,
    const float* __restrict__ W, int ldw,
    const float* __restrict__ bias,
    float* __restrict__ Cp, int ldc,
    const float* __restrict__ resid,
    int K, float alpha, int row0, int col0)
{
  __shared__ __align__(16) unsigned short sA[2][64 * 40];  // [hi/lo][row][k]
  __shared__ __align__(16) unsigned short sB[2][64 * 40];  // [hi/lo][col][k]
  const int tid = threadIdx.x;
  // staging indices
  const int ar  = tid >> 2;            // A row 0..63
  const int akq = (tid & 3) * 8;       // A k base
  const int bc  = tid & 63;            // B col 0..63
  const int bkq = (tid >> 6) * 8;      // B k base
  // mfma indices
  const int lane = tid & 63;
  const int wv   = tid >> 6;
  const int wr   = (wv >> 1) * 32;
  const int wc   = (wv & 1) * 32;
  const int frow = lane & 15;
  const int fk   = (lane >> 4) * 8;

  f32x4 acc[2][2];
  #pragma unroll
  for (int i = 0; i < 2; ++i)
    #pragma unroll
    for (int j = 0; j < 2; ++j)
      acc[i][j] = (f32x4){0.f, 0.f, 0.f, 0.f};

  for (int k0 = 0; k0 < K; k0 += 32) {
    // ---- stage A tile (64 rows x 32 k), split hi/lo ----
    {
      const float* ap = A + (size_t)(row0 + ar) * lda + (k0 + akq);
      float av[8];
      *(float4*)&av[0] = *(const float4*)ap;
      *(float4*)&av[4] = *(const float4*)(ap + 4);
      short8v vh, vl;
      #pragma unroll
      for (int j = 0; j < 8; ++j) {
        unsigned short h = bf_rne(av[j]);
        float hf = __uint_as_float(((unsigned)h) << 16);
        float d  = av[j] - hf;
        vh[j] = (short)h;
        vl[j] = (short)(__float_as_uint(d) >> 16);
      }
      *(short8v*)&sA[0][ar * 40 + akq] = vh;
      *(short8v*)&sA[1][ar * 40 + akq] = vl;
    }
    // ---- stage B tile (32 k x 64 cols) transposed to [col][k] ----
    {
      const float* wp = W + (size_t)(k0 + bkq) * ldw + (col0 + bc);
      float wv8[8];
      #pragma unroll
      for (int j = 0; j < 8; ++j) wv8[j] = wp[(size_t)j * ldw];
      short8v vh, vl;
      #pragma unroll
      for (int j = 0; j < 8; ++j) {
        unsigned short h = bf_rne(wv8[j]);
        float hf = __uint_as_float(((unsigned)h) << 16);
        float d  = wv8[j] - hf;
        vh[j] = (short)h;
        vl[j] = (short)(__float_as_uint(d) >> 16);
      }
      *(short8v*)&sB[0][bc * 40 + bkq] = vh;
      *(short8v*)&sB[1][bc * 40 + bkq] = vl;
    }
    __syncthreads();
    // ---- fragments + 12 MFMA ----
    short8v ah[2], al[2], bh[2], bl[2];
    #pragma unroll
    for (int rb = 0; rb < 2; ++rb) {
      int off = (wr + rb * 16 + frow) * 40 + fk;
      ah[rb] = *(const short8v*)&sA[0][off];
      al[rb] = *(const short8v*)&sA[1][off];
    }
    #pragma unroll
    for (int cb = 0; cb < 2; ++cb) {
      int off = (wc + cb * 16 + frow) * 40 + fk;
      bh[cb] = *(const short8v*)&sB[0][off];
      bl[cb] = *(const short8v*)&sB[1][off];
    }
    #pragma unroll
    for (int rb = 0; rb < 2; ++rb)
      #pragma unroll
      for (int cb = 0; cb < 2; ++cb) {
        acc[rb][cb] = __builtin_amdgcn_mfma_f32_16x16x32_bf16(ah[rb], bh[cb], acc[rb][cb], 0, 0, 0);
        acc[rb][cb] = __builtin_amdgcn_mfma_f32_16x16x32_bf16(ah[rb], bl[cb], acc[rb][cb], 0, 0, 0);
        acc[rb][cb] = __builtin_amdgcn_mfma_f32_16x16x32_bf16(al[rb], bh[cb], acc[rb][cb], 0, 0, 0);
      }
    __syncthreads();
  }
  // ---- epilogue: C/D layout col=lane&15, row=(lane>>4)*4+reg ----
  float bv[2];
  #pragma unroll
  for (int cb = 0; cb < 2; ++cb) bv[cb] = bias[col0 + wc + cb * 16 + frow];
  #pragma unroll
  for (int rb = 0; rb < 2; ++rb)
    #pragma unroll
    for (int cb = 0; cb < 2; ++cb) {
      int r0 = row0 + wr + rb * 16 + (lane >> 4) * 4;
      int cc = col0 + wc + cb * 16 + frow;
      #pragma unroll
      for (int j = 0; j < 4; ++j) {
        float v = alpha * (acc[rb][cb][j] + bv[cb]);
        if (RELU) v = fmaxf(v, 0.f);
        if (RESID) v += resid[(size_t)(r0 + j) * ldc + cc];
        Cp[(size_t)(r0 + j) * ldc + cc] = v;
      }
    }
}

// qkv: grid (4, 128, 3). M=8192 batched over all n.  q gets alpha=scale.
__global__ __launch_bounds__(256) void k_mfma_qkv(
    const float* __restrict__ enc,
    const float* __restrict__ wq, const float* __restrict__ bq,
    const float* __restrict__ wk, const float* __restrict__ bk,
    const float* __restrict__ wv, const float* __restrict__ bv,
    float* __restrict__ q, float* __restrict__ k, float* __restrict__ v, float scale)
{
  int pr = blockIdx.z;
  const float* W; const float* bias; float* out; float alpha = 1.f;
  if (pr == 0)      { W = wq; bias = bq; out = q; alpha = scale; }
  else if (pr == 1) { W = wk; bias = bk; out = k; }
  else              { W = wv; bias = bv; out = v; }
  mfma_core<false, false>(enc, Cd, W, Cd, bias, out, Cd, nullptr, Cd, alpha,
                          blockIdx.y * 64, blockIdx.x * 64);
}

// out-projection + residual: grid (4, 128)
__global__ __launch_bounds__(256) void k_mfma_out(
    const float* __restrict__ ob, const float* __restrict__ wo,
    const float* __restrict__ bo, float* __restrict__ enc)
{
  mfma_core<false, true>(ob, Cd, wo, Cd, bo, enc, Cd, enc, Cd, 1.f,
                         blockIdx.y * 64, blockIdx.x * 64);
}

// mlp in (relu): grid (16, 128)
__global__ __launch_bounds__(256) void k_mfma_mlpin(
    const float* __restrict__ enc, const float* __restrict__ win,
    const float* __restrict__ bin, float* __restrict__ h)
{
  mfma_core<true, false>(enc, Cd, win, Md, bin, h, Md, nullptr, Cd, 1.f,
                         blockIdx.y * 64, blockIdx.x * 64);
}

// mlp out + residual: grid (4, 128), K=1024
__global__ __launch_bounds__(256) void k_mfma_mlpout(
    const float* __restrict__ h, const float* __restrict__ wout,
    const float* __restrict__ bout, float* __restrict__ enc)
{
  mfma_core<false, true>(h, Md, wout, Cd, bout, enc, Cd, enc, Md, 1.f,
                         blockIdx.y * 64, blockIdx.x * 64);
}

// =====================================================================
// LayerNorm in-place over C=256, wave per row.
// =====================================================================
__global__ __launch_bounds__(256) void k_ln(float* __restrict__ enc,
    const float* __restrict__ s, const float* __restrict__ b2)
{
  int tid = threadIdx.x;
  int r = blockIdx.x * 4 + (tid >> 6);
  int lane = tid & 63;
  float* row = enc + (size_t)r * Cd;
  float4 v = ((float4*)row)[lane];
  float p = v.x + v.y + v.z + v.w;
  #pragma unroll
  for (int m = 1; m < 64; m <<= 1) p += __shfl_xor(p, m);
  float mu = p * (1.f / 256.f);
  float dx = v.x - mu, dy = v.y - mu, dz = v.z - mu, dw = v.w - mu;
  float q = dx*dx + dy*dy + dz*dz + dw*dw;
  #pragma unroll
  for (int m = 1; m < 64; m <<= 1) q += __shfl_xor(q, m);
  float rstd = rsqrtf(q * (1.f / 256.f) + 1e-6f);
  float4 sv = ((const float4*)s)[lane];
  float4 bv = ((const float4*)b2)[lane];
  v.x = sv.x * dx * rstd + bv.x;
  v.y = sv.y * dy * rstd + bv.y;
  v.z = sv.z * dz * rstd + bv.z;
  v.w = sv.w * dw * rstd + bv.w;
  ((float4*)row)[lane] = v;
}

// =====================================================================
// Attention, key-split flash style (verified round 4).
// =====================================================================
template<int CROSS>
__global__ __launch_bounds__(256) void k_attn_part(
    const float* __restrict__ qb, const float* __restrict__ kb,
    const float* __restrict__ vb,
    const float* __restrict__ pair, const float* __restrict__ pairT,
    const float* __restrict__ bw_p, const float* __restrict__ bb_p,
    const int* __restrict__ ulp, const int* __restrict__ elp,
    float* __restrict__ po, float* __restrict__ pml)
{
  __shared__ float ks_[32][32];
  __shared__ float vs_[32][32];
  const int tid = threadIdx.x;
  const int n = blockIdx.x, h = blockIdx.y, kspl = blockIdx.z;
  const int b = n >> 1, s = n & 1;
  const int u_len = ulp[0], e_len = elp[0];
  const int nkv = CROSS ? (n ^ 1) : n;
  const int qlen  = s ? e_len : u_len;
  const int kvlen = CROSS ? (s ? u_len : e_len) : qlen;
  const int k0base = kspl * 64;
  const float* qp = qb + (size_t)n   * Ll * Cd + h * Dd;
  const float* kp = kb + (size_t)nkv * Ll * Cd + h * Dd;
  const float* vp = vb + (size_t)nkv * Ll * Cd + h * Dd;
  float bw = 0.f, bbias = 0.f;
  const float* prow = nullptr;
  if (CROSS) {
    bw = bw_p[0]; bbias = bb_p[0];
    prow = (s == 0 ? pair : pairT) + ((size_t)b * Ll + tid) * Ll;
  }

  float qv[32];
  {
    const float4* q4 = (const float4*)(qp + (size_t)tid * Cd);
    #pragma unroll
    for (int t = 0; t < 8; ++t) {
      float4 x = q4[t];
      qv[4*t] = x.x; qv[4*t+1] = x.y; qv[4*t+2] = x.z; qv[4*t+3] = x.w;
    }
  }
  const bool qvalid = tid < qlen;
  float m = NEG_HUGE, l = 0.f;
  float oa[32];
  #pragma unroll
  for (int d = 0; d < 32; ++d) oa[d] = 0.f;

  #pragma unroll
  for (int cc = 0; cc < 2; ++cc) {
    const int c0 = k0base + cc * 32;
    __syncthreads();
    #pragma unroll
    for (int t = 0; t < 4; ++t) {
      int idx = t * 256 + tid;
      int r = idx >> 5, d = idx & 31;
      ks_[r][d] = kp[(size_t)(c0 + r) * Cd + d];
      vs_[r][d] = vp[(size_t)(c0 + r) * Cd + d];
    }
    float pr[32];
    if (CROSS) {
      const float4* p4 = (const float4*)(prow + c0);
      #pragma unroll
      for (int t = 0; t < 8; ++t) {
        float4 x = p4[t];
        pr[4*t] = x.x; pr[4*t+1] = x.y; pr[4*t+2] = x.z; pr[4*t+3] = x.w;
      }
    }
    __syncthreads();
    #pragma unroll 2
    for (int ec = 0; ec < 32; ++ec) {
      int e = c0 + ec;
      float s0 = 0.f, s1 = 0.f, s2 = 0.f, s3 = 0.f;
      const float4* kr = (const float4*)&ks_[ec][0];
      #pragma unroll
      for (int t = 0; t < 8; ++t) {
        float4 kx = kr[t];
        s0 = fmaf(qv[4*t],   kx.x, s0);
        s1 = fmaf(qv[4*t+1], kx.y, s1);
        s2 = fmaf(qv[4*t+2], kx.z, s2);
        s3 = fmaf(qv[4*t+3], kx.w, s3);
      }
      float sd = (s0 + s1) + (s2 + s3);
      if (CROSS) sd = fmaf(bw, pr[ec], sd + bbias);
      bool valid = qvalid && (e < kvlen);
      float sv = valid ? sd : NEG_HUGE;
      if (sv > m) {
        float corr = __expf(m - sv);
        l *= corr;
        #pragma unroll
        for (int d = 0; d < 32; ++d) oa[d] *= corr;
        m = sv;
      }
      float p = __expf(sv - m);
      l += p;
      const float4* vr = (const float4*)&vs_[ec][0];
      #pragma unroll
      for (int t = 0; t < 8; ++t) {
        float4 vx = vr[t];
        oa[4*t]   = fmaf(p, vx.x, oa[4*t]);
        oa[4*t+1] = fmaf(p, vx.y, oa[4*t+1]);
        oa[4*t+2] = fmaf(p, vx.z, oa[4*t+2]);
        oa[4*t+3] = fmaf(p, vx.w, oa[4*t+3]);
      }
    }
  }
  size_t pidx = (((size_t)(n * Hh + h) * KS + kspl) * Ll + tid);
  float* pop = po + pidx * Dd;
  #pragma unroll
  for (int t = 0; t < 8; ++t) {
    float4 x = {oa[4*t], oa[4*t+1], oa[4*t+2], oa[4*t+3]};
    ((float4*)pop)[t] = x;
  }
  pml[pidx * 2]     = m;
  pml[pidx * 2 + 1] = l;
}

// merge: grid (2B, H), 256 thr; thread = query row.
template<int CROSS>
__global__ __launch_bounds__(256) void k_attn_merge(
    const float* __restrict__ po, const float* __restrict__ pml,
    float* __restrict__ ob,
    const int* __restrict__ ulp, const int* __restrict__ elp)
{
  const int tid = threadIdx.x;
  const int n = blockIdx.x, h = blockIdx.y;
  const int s = n & 1;
  const int qlen = s ? elp[0] : ulp[0];
  size_t base = ((size_t)(n * Hh + h) * KS) * Ll + tid;
  float ms[KS], ls[KS];
  #pragma unroll
  for (int i = 0; i < KS; ++i) {
    ms[i] = pml[(base + (size_t)i * Ll) * 2];
    ls[i] = pml[(base + (size_t)i * Ll) * 2 + 1];
  }
  float M = ms[0];
  #pragma unroll
  for (int i = 1; i < KS; ++i) M = fmaxf(M, ms[i]);
  float w[KS]; float L = 0.f;
  #pragma unroll
  for (int i = 0; i < KS; ++i) { w[i] = __expf(ms[i] - M); L += ls[i] * w[i]; }
  float oa[32];
  #pragma unroll
  for (int d = 0; d < 32; ++d) oa[d] = 0.f;
  #pragma unroll
  for (int i = 0; i < KS; ++i) {
    const float4* p4 = (const float4*)(po + (base + (size_t)i * Ll) * Dd);
    float wi = w[i];
    #pragma unroll
    for (int t = 0; t < 8; ++t) {
      float4 x = p4[t];
      oa[4*t]   = fmaf(wi, x.x, oa[4*t]);
      oa[4*t+1] = fmaf(wi, x.y, oa[4*t+1]);
      oa[4*t+2] = fmaf(wi, x.z, oa[4*t+2]);
      oa[4*t+3] = fmaf(wi, x.w, oa[4*t+3]);
    }
  }
  float om = 1.f / L;
  if (CROSS && tid >= qlen) om = 0.f;   // cross: ue_m post-mask zeroes invalid rows
  float* op = ob + ((size_t)n * Ll + tid) * Cd + h * Dd;
  #pragma unroll
  for (int t = 0; t < 8; ++t) {
    float4 x = {oa[4*t] * om, oa[4*t+1] * om, oa[4*t+2] * om, oa[4*t+3] * om};
    ((float4*)op)[t] = x;
  }
}

// =====================================================================
// Embedding + PE + mask. grid 8192 x 256
// =====================================================================
__global__ __launch_bounds__(256) void k_embed(
    const float* __restrict__ u_in, const float* __restrict__ e_in,
    const float* __restrict__ emb_w, const float* __restrict__ emb_b,
    const int* __restrict__ ulp, const int* __restrict__ elp,
    float* __restrict__ enc)
{
  int gid = blockIdx.x * 256 + threadIdx.x;
  int c = gid & 255;
  int row = (gid >> 8) & 255;
  int n = gid >> 16;
  int b = n >> 1, s = n & 1;
  const float* x = (s ? e_in : u_in) + ((size_t)b * Ll + row) * FINd;
  float acc = emb_b[c];
  #pragma unroll
  for (int f = 0; f < FINd; ++f) acc = fmaf(x[f], emb_w[f * Cd + c], acc);
  const float k2 = 0.051902826f;  // log2(10000)/256
  float dv = exp2f(-k2 * (float)(2 * (c >> 1)));
  float ang = (float)row * dv;
  float pe = ((c & 1) == 0) ? sinf(ang) : cosf(ang);
  int len = s ? elp[0] : ulp[0];
  enc[gid] = (row < len) ? (acc + pe) : 0.f;
}

// pair = logit(bpp); also writes pairT. grid (B,8,8), 32x32 tile per block.
__global__ __launch_bounds__(256) void k_pairinit(
    const float* __restrict__ bpp, float* __restrict__ pair, float* __restrict__ pairT)
{
  __shared__ float tile[32][33];
  const int tid = threadIdx.x;
  const int b = blockIdx.x;
  const int u0 = blockIdx.y * 32, e0 = blockIdx.z * 32;
  #pragma unroll
  for (int t = 0; t < 4; ++t) {
    int idx = t * 256 + tid;
    int r = idx >> 5, c = idx & 31;
    float v = bpp[((size_t)b * Ll + u0 + r) * Ll + e0 + c];
    float val = logf(v + 1e-3f) - logf(1.f - v + 1e-3f);
    pair[((size_t)b * Ll + u0 + r) * Ll + e0 + c] = val;
    tile[r][c] = val;
  }
  __syncthreads();
  #pragma unroll
  for (int t = 0; t < 4; ++t) {
    int idx = t * 256 + tid;
    int r = idx >> 5, c = idx & 31;
    pairT[((size_t)b * Ll + e0 + r) * Ll + u0 + c] = tile[c][r];
  }
}

// proj to P=32 columns. grid 1024 x 256
__global__ __launch_bounds__(256) void k_proj32(
    const float* __restrict__ enc, const float* __restrict__ Wp,
    const float* __restrict__ bp, float* __restrict__ sp)
{
  int gid = blockIdx.x * 256 + threadIdx.x;
  int p = gid & 31;
  int grow = gid >> 5;
  const float4* x4 = (const float4*)(enc + (size_t)grow * Cd);
  float acc = bp[p];
  for (int c4 = 0; c4 < 64; ++c4) {
    float4 xv = x4[c4];
    int cb = c4 * 4;
    acc = fmaf(xv.x, Wp[(cb    ) * Pp + p], acc);
    acc = fmaf(xv.y, Wp[(cb + 1) * Pp + p], acc);
    acc = fmaf(xv.z, Wp[(cb + 2) * Pp + p], acc);
    acc = fmaf(xv.w, Wp[(cb + 3) * Pp + p], acc);
  }
  sp[(size_t)grow * Pp + p] = acc;
}

// MODE 0: pair += w * mask * (su@se^T)   (also maintains pairT)
// MODE 1: gate = mask ? sigmoid(w*pair + b + su@se^T) : 0
template<int MODE>
__global__ __launch_bounds__(256) void k_pairop(
    const float* __restrict__ sp, float* __restrict__ pair, float* __restrict__ pairT,
    float* __restrict__ gate,
    const float* __restrict__ w_p, const float* __restrict__ b_p,
    const int* __restrict__ ulp, const int* __restrict__ elp)
{
  __shared__ float su[32][36];
  __shared__ float se[32][36];
  const int tid = threadIdx.x;
  const int b = blockIdx.z;
  const int u0 = blockIdx.y * 64, e0 = blockIdx.x * 64;
  const float* spu = sp + ((size_t)(b * 2 + 0) * Ll + u0) * Pp;
  const float* spe = sp + ((size_t)(b * 2 + 1) * Ll + e0) * Pp;
  #pragma unroll
  for (int t = 0; t < 8; ++t) {
    int idx = t * 256 + tid;
    int r = idx >> 5, p = idx & 31;
    su[p][r] = spu[r * Pp + p];
    se[p][r] = spe[r * Pp + p];
  }
  __syncthreads();
  const int tr = tid >> 4, tc = tid & 15;
  float acc[4][4] = {};
  #pragma unroll
  for (int p = 0; p < 32; ++p) {
    float4 av = *(const float4*)&su[p][tr * 4];
    float4 bv = *(const float4*)&se[p][tc * 4];
    float aa[4] = {av.x, av.y, av.z, av.w};
    float bb[4] = {bv.x, bv.y, bv.z, bv.w};
    #pragma unroll
    for (int i = 0; i < 4; ++i)
      #pragma unroll
      for (int j = 0; j < 4; ++j)
        acc[i][j] = fmaf(aa[i], bb[j], acc[i][j]);
  }
  const int u_len = ulp[0], e_len = elp[0];
  const float w = w_p[0];
  const float bb2 = MODE ? b_p[0] : 0.f;
  float res[4][4];
  #pragma unroll
  for (int i = 0; i < 4; ++i) {
    int u = u0 + tr * 4 + i;
    bool uval = u < u_len;
    size_t off = ((size_t)b * Ll + u) * Ll + e0 + tc * 4;
    float4 prv = *(const float4*)&pair[off];
    float pv[4] = {prv.x, prv.y, prv.z, prv.w};
    #pragma unroll
    for (int j = 0; j < 4; ++j) {
      bool valid = uval && ((e0 + tc * 4 + j) < e_len);
      if (MODE == 0) {
        res[i][j] = pv[j] + w * (valid ? acc[i][j] : 0.f);
      } else {
        float z = fmaf(w, pv[j], bb2) + acc[i][j];
        res[i][j] = valid ? (1.f / (1.f + expf(-z))) : 0.f;
      }
    }
    float4 ov = {res[i][0], res[i][1], res[i][2], res[i][3]};
    if (MODE == 0) *(float4*)&pair[off] = ov;
    else           *(float4*)&gate[off] = ov;
  }
  if (MODE == 0) {
    #pragma unroll
    for (int j = 0; j < 4; ++j) {
      size_t offt = ((size_t)b * Ll + e0 + tc * 4 + j) * Ll + u0 + tr * 4;
      float4 tv = {res[0][j], res[1][j], res[2][j], res[3][j]};
      *(float4*)&pairT[offt] = tv;
    }
  }
}

// gate row/col sums. grid B x 256
__global__ __launch_bounds__(256) void k_sums(
    const float* __restrict__ gate, float* __restrict__ gu, float* __restrict__ ge)
{
  int b = blockIdx.x, tid = threadIdx.x;
  const float* g = gate + (size_t)b * Ll * Ll;
  float acc = 0.f;
  for (int u = 0; u < Ll; ++u) acc += g[(size_t)u * Ll + tid];
  ge[b * Ll + tid] = acc;
  int wave = tid >> 6, lane = tid & 63;
  for (int r = wave; r < Ll; r += 4) {
    const float* gr = g + (size_t)r * Ll;
    float p = gr[lane] + gr[64 + lane] + gr[128 + lane] + gr[192 + lane];
    #pragma unroll
    for (int m = 1; m < 64; m <<= 1) p += __shfl_xor(p, m);
    if (lane == 0) gu[b * Ll + r] = p;
  }
}

// indel gates. grid 2048 x 256
__global__ __launch_bounds__(256) void k_ug(
    const float* __restrict__ enc, const float* __restrict__ gw,
    const float* __restrict__ gb, const int* __restrict__ ulp,
    const int* __restrict__ elp, float* __restrict__ ug)
{
  int tid = threadIdx.x;
  int gr = blockIdx.x * 4 + (tid >> 6);
  int lane = tid & 63;
  int n = gr >> 8, row = gr & 255;
  int s = n & 1;
  const float* x = enc + (size_t)gr * Cd;
  float p = 0.f;
  #pragma unroll
  for (int t = 0; t < 4; ++t) p = fmaf(x[lane + 64 * t], gw[lane + 64 * t], p);
  #pragma unroll
  for (int m = 1; m < 64; m <<= 1) p += __shfl_xor(p, m);
  if (lane == 0) {
    int u_len = ulp[0], e_len = elp[0];
    int mylen = s ? e_len : u_len;
    int other = s ? u_len : e_len;
    bool valid = (row < mylen) && (other > 0);
    ug[gr] = valid ? (1.f / (1.f + expf(-(p + gb[0])))) : 0.f;
  }
}

// feature vector. grid (B,4) x 256
__global__ __launch_bounds__(256) void k_feats(
    const float* __restrict__ enc, const float* __restrict__ gu,
    const float* __restrict__ ge, const float* __restrict__ ug,
    const float* __restrict__ oh, const float* __restrict__ he,
    float* __restrict__ fv)
{
  int b = blockIdx.x, which = blockIdx.y, c = threadIdx.x;
  const float* x; const float* wv; int dst;
  if (which == 0)      { x = enc + (size_t)(b*2+0)*Ll*Cd; wv = gu + b*Ll;       dst = 0;   }
  else if (which == 1) { x = enc + (size_t)(b*2+1)*Ll*Cd; wv = ge + b*Ll;       dst = 256; }
  else if (which == 2) { x = enc + (size_t)(b*2+0)*Ll*Cd; wv = ug + (b*2+0)*Ll; dst = 512; }
  else                 { x = enc + (size_t)(b*2+1)*Ll*Cd; wv = ug + (b*2+1)*Ll; dst = 768; }
  float acc = 0.f;
  for (int r = 0; r < Ll; ++r) acc = fmaf(wv[r], x[(size_t)r * Cd + c], acc);
  fv[(size_t)b * Fd + dst + c] = acc;
  if (which == 0) {
    if (c < OHd) fv[(size_t)b * Fd + 1024 + c] = oh[b * OHd + c];
    if (c == 32) fv[(size_t)b * Fd + 1056] = he[b];
  }
}

// output head. grid B x 256. od-GEMV split 4-way across waves.
__global__ __launch_bounds__(256) void k_head(
    const float* __restrict__ fv, const float* __restrict__ on_s,
    const float* __restrict__ on_b, const float* __restrict__ od_w,
    const float* __restrict__ od_b, const float* __restrict__ ow_w,
    const float* __restrict__ ow_b, float* __restrict__ outp)
{
  __shared__ float fs[Fd];
  __shared__ float ys[OUTd];
  __shared__ float red[4];
  __shared__ float psum[4][OUTd];
  int b = blockIdx.x, tid = threadIdx.x;
  for (int i = tid; i < Fd; i += 256) fs[i] = fv[(size_t)b * Fd + i];
  __syncthreads();
  float part = 0.f;
  for (int i = tid; i < Fd; i += 256) part += fs[i];
  #pragma unroll
  for (int m = 1; m < 64; m <<= 1) part += __shfl_xor(part, m);
  if ((tid & 63) == 0) red[tid >> 6] = part;
  __syncthreads();
  float mu = (red[0] + red[1] + red[2] + red[3]) * (1.f / (float)Fd);
  __syncthreads();
  float p2 = 0.f;
  for (int i = tid; i < Fd; i += 256) { float d = fs[i] - mu; p2 = fmaf(d, d, p2); }
  #pragma unroll
  for (int m = 1; m < 64; m <<= 1) p2 += __shfl_xor(p2, m);
  if ((tid & 63) == 0) red[tid >> 6] = p2;
  __syncthreads();
  float rstd = rsqrtf((red[0] + red[1] + red[2] + red[3]) * (1.f / (float)Fd) + 1e-6f);
  __syncthreads();
  for (int i = tid; i < Fd; i += 256)
    fs[i] = on_s[i] * (fs[i] - mu) * rstd + on_b[i];
  __syncthreads();
  // od GEMV: wave wvi covers f in [wvi*265, min(Fd,(wvi+1)*265)), 4 cols per thread
  int wvi = tid >> 6, ln = tid & 63;
  int f0 = wvi * 265;
  int f1 = (f0 + 265 < Fd) ? (f0 + 265) : Fd;
  float a0 = 0.f, a1 = 0.f, a2 = 0.f, a3 = 0.f;
  for (int f = f0; f < f1; ++f) {
    float x = fs[f];
    const float* wrow = od_w + (size_t)f * OUTd + ln;
    a0 = fmaf(x, wrow[0],   a0);
    a1 = fmaf(x, wrow[64],  a1);
    a2 = fmaf(x, wrow[128], a2);
    a3 = fmaf(x, wrow[192], a3);
  }
  psum[wvi][ln]       = a0;
  psum[wvi][64 + ln]  = a1;
  psum[wvi][128 + ln] = a2;
  psum[wvi][192 + ln] = a3;
  __syncthreads();
  float acc = od_b[tid] + psum[0][tid] + psum[1][tid] + psum[2][tid] + psum[3][tid];
  ys[tid] = fmaxf(acc, 0.f);
  __syncthreads();
  if (tid < 3) {
    float o = ow_b[tid];
    for (int i = 0; i < OUTd; ++i) o = fmaf(ys[i], ow_w[i * 3 + tid], o);
    outp[b * 3 + tid] = o;
  }
}

// =====================================================================
extern "C" void kernel_launch(void* const* d_in, const int* in_sizes, int n_in,
                              void* d_out, int out_size, void* d_ws, size_t ws_size,
                              hipStream_t stream)
{
  const float* u_in   = (const float*)d_in[0];
  const float* e_in   = (const float*)d_in[1];
  const float* bpp    = (const float*)d_in[2];
  const float* oh     = (const float*)d_in[3];
  const float* he     = (const float*)d_in[4];
  const int*   ulp    = (const int*)d_in[5];
  const int*   elp    = (const int*)d_in[6];
  const float* emb_w  = (const float*)d_in[7];
  const float* emb_b  = (const float*)d_in[8];
  const float* ca_wq  = (const float*)d_in[9];
  const float* ca_wq_b= (const float*)d_in[10];
  const float* ca_wk  = (const float*)d_in[11];
  const float* ca_wk_b= (const float*)d_in[12];
  const float* ca_wv  = (const float*)d_in[13];
  const float* ca_wv_b= (const float*)d_in[14];
  const float* ca_wo  = (const float*)d_in[15];
  const float* ca_wo_b= (const float*)d_in[16];
  const float* ca_bw  = (const float*)d_in[17];
  const float* ca_bb  = (const float*)d_in[18];
  const float* sa_wq  = (const float*)d_in[19];
  const float* sa_wq_b= (const float*)d_in[20];
  const float* sa_wk  = (const float*)d_in[21];
  const float* sa_wk_b= (const float*)d_in[22];
  const float* sa_wv  = (const float*)d_in[23];
  const float* sa_wv_b= (const float*)d_in[24];
  const float* sa_wo  = (const float*)d_in[25];
  const float* sa_wo_b= (const float*)d_in[26];
  const float* mi_w   = (const float*)d_in[27];
  const float* mi_b   = (const float*)d_in[28];
  const float* mo_w   = (const float*)d_in[29];
  const float* mo_b   = (const float*)d_in[30];
  const float* cn_s   = (const float*)d_in[31];
  const float* cn_b   = (const float*)d_in[32];
  const float* sn_s   = (const float*)d_in[33];
  const float* sn_b   = (const float*)d_in[34];
  const float* mn_s   = (const float*)d_in[35];
  const float* mn_b   = (const float*)d_in[36];
  const float* pair_w = (const float*)d_in[37];
  const float* pu_w   = (const float*)d_in[38];
  const float* pu_b   = (const float*)d_in[39];
  const float* so_bw  = (const float*)d_in[40];
  const float* so_bb  = (const float*)d_in[41];
  const float* so_w   = (const float*)d_in[42];
  const float* so_b   = (const float*)d_in[43];
  const float* gate_w = (const float*)d_in[44];
  const float* gate_b = (const float*)d_in[45];
  const float* on_s   = (const float*)d_in[46];
  const float* on_b   = (const float*)d_in[47];
  const float* od_w   = (const float*)d_in[48];
  const float* od_b   = (const float*)d_in[49];
  const float* ow_w   = (const float*)d_in[50];
  const float* ow_b   = (const float*)d_in[51];

  float* ws    = (float*)d_ws;
  float* enc   = ws + WS_ENC;
  float* pair  = ws + WS_PAIR;
  float* pairT = ws + WS_PAIRT;
  float* big   = ws + WS_BIG;
  float* qb    = big;
  float* kb    = big + 2097152;
  float* vb    = big + 4194304;
  float* ob    = big + 6291456;
  float* hb    = big;           // mlp hidden reuses q/k/v/o region
  float* gate  = big;           // final-stage gate reuses region
  float* po    = ws + WS_PO;
  float* pml   = ws + WS_PML;
  float* sp    = ws + WS_SP;
  float* gu    = ws + WS_GU;
  float* ge    = ws + WS_GE;
  float* ug    = ws + WS_UG;
  float* fv    = ws + WS_FV;

  const float sc = 1.0f / sqrtf((float)Dd);

  k_embed<<<8192, 256, 0, stream>>>(u_in, e_in, emb_w, emb_b, ulp, elp, enc);
  k_pairinit<<<dim3(Bb,8,8), 256, 0, stream>>>(bpp, pair, pairT);

  for (int it = 0; it < 8; ++it) {
    int wi = it & 3;
    size_t wcc = (size_t)wi * Cd * Cd;     // C*H*D == C*C
    // ---- cross attention ----
    k_mfma_qkv<<<dim3(4,128,3), 256, 0, stream>>>(enc,
        ca_wq + wcc, ca_wq_b + wi*Cd, ca_wk + wcc, ca_wk_b + wi*Cd,
        ca_wv + wcc, ca_wv_b + wi*Cd, qb, kb, vb, sc);
    k_attn_part<1><<<dim3(32,Hh,KS), 256, 0, stream>>>(qb, kb, vb, pair, pairT,
        ca_bw + wi, ca_bb + wi, ulp, elp, po, pml);
    k_attn_merge<1><<<dim3(32,Hh), 256, 0, stream>>>(po, pml, ob, ulp, elp);
    k_mfma_out<<<dim3(4,128), 256, 0, stream>>>(ob, ca_wo + wcc, ca_wo_b + wi*Cd, enc);
    k_ln<<<2048, 256, 0, stream>>>(enc, cn_s + wi*Cd, cn_b + wi*Cd);
    // ---- self attention ----
    k_mfma_qkv<<<dim3(4,128,3), 256, 0, stream>>>(enc,
        sa_wq + wcc, sa_wq_b + wi*Cd, sa_wk + wcc, sa_wk_b + wi*Cd,
        sa_wv + wcc, sa_wv_b + wi*Cd, qb, kb, vb, sc);
    k_attn_part<0><<<dim3(32,Hh,KS), 256, 0, stream>>>(qb, kb, vb, nullptr, nullptr,
        nullptr, nullptr, ulp, elp, po, pml);
    k_attn_merge<0><<<dim3(32,Hh), 256, 0, stream>>>(po, pml, ob, ulp, elp);
    k_mfma_out<<<dim3(4,128), 256, 0, stream>>>(ob, sa_wo + wcc, sa_wo_b + wi*Cd, enc);
    k_ln<<<2048, 256, 0, stream>>>(enc, sn_s + wi*Cd, sn_b + wi*Cd);
    // ---- MLP ----
    k_mfma_mlpin<<<dim3(16,128), 256, 0, stream>>>(enc,
        mi_w + (size_t)wi*Cd*Md, mi_b + (size_t)wi*Md, hb);
    k_mfma_mlpout<<<dim3(4,128), 256, 0, stream>>>(hb,
        mo_w + (size_t)wi*Md*Cd, mo_b + wi*Cd, enc);
    k_ln<<<2048, 256, 0, stream>>>(enc, mn_s + wi*Cd, mn_b + wi*Cd);
    // ---- pair outer-product update (maintains pair AND pairT) ----
    k_proj32<<<1024, 256, 0, stream>>>(enc, pu_w + (size_t)wi*Cd*Pp, pu_b + wi*Pp, sp);
    k_pairop<0><<<dim3(4,4,Bb), 256, 0, stream>>>(sp, pair, pairT, nullptr,
        pair_w + wi, nullptr, ulp, elp);
  }

  // ---- outputs ----
  k_proj32<<<1024, 256, 0, stream>>>(enc, so_w, so_b, sp);
  k_pairop<1><<<dim3(4,4,Bb), 256, 0, stream>>>(sp, pair, pairT, gate, so_bw, so_bb, ulp, elp);
  k_sums<<<Bb, 256, 0, stream>>>(gate, gu, ge);
  k_ug<<<2048, 256, 0, stream>>>(enc, gate_w, gate_b, ulp, elp, ug);
  k_feats<<<dim3(Bb,4), 256, 0, stream>>>(enc, gu, ge, ug, oh, he, fv);
  k_head<<<Bb, 256, 0, stream>>>(fv, on_s, on_b, od_w, od_b, ow_w, ow_b, (float*)d_out);
}